// Round 8
// baseline (344.222 us; speedup 1.0000x reference)
//
#include <hip/hip_runtime.h>
#include <hip/hip_bf16.h>

typedef __hip_bfloat16 bf16;
typedef unsigned short u16;
typedef __attribute__((ext_vector_type(8))) short short8;
typedef __attribute__((ext_vector_type(4))) float f32x4;

#define HW 4096
#define NB (64*HW)

__device__ __forceinline__ f32x4 MFMA16(short8 a, short8 b, f32x4 c){
  return __builtin_amdgcn_mfma_f32_16x16x32_bf16(a, b, c, 0, 0, 0);
}

__device__ __forceinline__ short f2bf(float f){
  bf16 h = __float2bfloat16(f);
  return *(short*)&h;          // scalar pun — promoted to register (round-0 verified)
}

// diagnostic fill (fp32 output)
__global__ __launch_bounds__(256) void k_const(float* __restrict__ out, float v, int n){
  int i = blockIdx.x*256 + threadIdx.x;
  if (i < n) out[i] = v;
}

// ---------------- BN fold ----------------
// bn: [0,64) invp | [64,128) biasp | [128,192) invc | [192,256) biasc | [256,768) invo | [768,1280) biaso
__global__ __launch_bounds__(512) void k_prep(
    const float* __restrict__ gp, const float* __restrict__ bp,
    const float* __restrict__ mp, const float* __restrict__ vp,
    const float* __restrict__ gc, const float* __restrict__ bc,
    const float* __restrict__ mc, const float* __restrict__ vc,
    const float* __restrict__ go, const float* __restrict__ bo,
    const float* __restrict__ mo, const float* __restrict__ vo,
    float* __restrict__ bn){
  int t = threadIdx.x;
  if (t < 64){
    float iv = gp[t] * rsqrtf(vp[t] + 1e-5f);
    bn[t] = iv; bn[64+t] = bp[t] - mp[t]*iv;
    float ic = gc[t] * rsqrtf(vc[t] + 1e-5f);
    bn[128+t] = ic; bn[192+t] = bc[t] - mc[t]*ic;
  }
  float io = go[t] * rsqrtf(vo[t] + 1e-5f);
  bn[256+t] = io; bn[768+t] = bo[t] - mo[t]*io;
}

// ---------------- conv_in: 512->64 x2, BN folded, LDS weights ----------------
// grid (16 ptiles of 256 px, 8 cgroups, 4 b); cg<4 -> fp(wp1), cg>=4 -> fcb(wc1)
__global__ __launch_bounds__(256) void k_conv_in(
    const float* __restrict__ x, const float* __restrict__ wp1, const float* __restrict__ wc1,
    const float* __restrict__ bn, float* __restrict__ fp, float* __restrict__ fcb){
  __shared__ __align__(16) float Wl[512][16];
  const int t = threadIdx.x;
  const int cg = blockIdx.y, b = blockIdx.z;
  const bool isP = cg < 4;
  const int c0 = (cg & 3) * 16;
  const float* w = isP ? wp1 : wc1;
  const float* inv  = isP ? bn       : bn + 128;
  const float* bias = isP ? bn + 64  : bn + 192;
  float* outp = isP ? fp : fcb;
  for (int i = t; i < 8192; i += 256){
    int c = i & 15, k = i >> 4;
    Wl[k][c] = w[(size_t)(c0 + c)*512 + k];
  }
  __syncthreads();
  const int p = blockIdx.x*256 + t;
  const float* xb = x + (size_t)b*512*HW + p;
  float acc[16];
  #pragma unroll
  for (int i = 0; i < 16; i++) acc[i] = 0.f;
  for (int k = 0; k < 512; k++){
    float xv = xb[(size_t)k*HW];
    float4 w0 = *(const float4*)&Wl[k][0];
    float4 w1 = *(const float4*)&Wl[k][4];
    float4 w2 = *(const float4*)&Wl[k][8];
    float4 w3 = *(const float4*)&Wl[k][12];
    acc[0]=fmaf(w0.x,xv,acc[0]); acc[1]=fmaf(w0.y,xv,acc[1]); acc[2]=fmaf(w0.z,xv,acc[2]); acc[3]=fmaf(w0.w,xv,acc[3]);
    acc[4]=fmaf(w1.x,xv,acc[4]); acc[5]=fmaf(w1.y,xv,acc[5]); acc[6]=fmaf(w1.z,xv,acc[6]); acc[7]=fmaf(w1.w,xv,acc[7]);
    acc[8]=fmaf(w2.x,xv,acc[8]); acc[9]=fmaf(w2.y,xv,acc[9]); acc[10]=fmaf(w2.z,xv,acc[10]); acc[11]=fmaf(w2.w,xv,acc[11]);
    acc[12]=fmaf(w3.x,xv,acc[12]); acc[13]=fmaf(w3.y,xv,acc[13]); acc[14]=fmaf(w3.z,xv,acc[14]); acc[15]=fmaf(w3.w,xv,acc[15]);
  }
  const size_t base = (size_t)b*NB + p;
  #pragma unroll
  for (int i = 0; i < 16; i++){
    int c = c0 + i;
    outp[base + (size_t)c*HW] = fmaf(acc[i], inv[c], bias[c]);
  }
}

// ---------------- QKV convs; Q,K transposed [p][c], V natural [c][p] ----------------
// grid (8 ptiles of 512, 12 = 3 mats * 4 cgroups, 4 b)
__global__ __launch_bounds__(256) void k_qkv(
    const float* __restrict__ fp,
    const float* __restrict__ wb,  const float* __restrict__ bbv,
    const float* __restrict__ wc2, const float* __restrict__ bc2,
    const float* __restrict__ wd,  const float* __restrict__ bd,
    bf16* __restrict__ fB, bf16* __restrict__ fC, bf16* __restrict__ fD){
  __shared__ __align__(16) float Wl[64][16];
  __shared__ float Bl[16];
  const int t = threadIdx.x;
  const int mg = blockIdx.y, mat = mg >> 2, c0 = (mg & 3)*16, b = blockIdx.z;
  const float* w    = (mat == 0) ? wb  : (mat == 1 ? wc2 : wd);
  const float* bias = (mat == 0) ? bbv : (mat == 1 ? bc2 : bd);
  bf16* outp        = (mat == 0) ? fB  : (mat == 1 ? fC  : fD);
  for (int i = t; i < 1024; i += 256){
    int c = i & 15, k = i >> 4;
    Wl[k][c] = w[(size_t)(c0 + c)*64 + k];
  }
  if (t < 16) Bl[t] = bias[c0 + t];
  __syncthreads();
  const int p = blockIdx.x*512 + t*2;
  const float* in = fp + (size_t)b*NB + p;
  float2 acc[16];
  #pragma unroll
  for (int i = 0; i < 16; i++){ acc[i].x = 0.f; acc[i].y = 0.f; }
  for (int k = 0; k < 64; k++){
    float2 xv = *(const float2*)(in + (size_t)k*HW);
    float4 w0 = *(const float4*)&Wl[k][0];
    float4 w1 = *(const float4*)&Wl[k][4];
    float4 w2 = *(const float4*)&Wl[k][8];
    float4 w3 = *(const float4*)&Wl[k][12];
    float wv[16] = {w0.x,w0.y,w0.z,w0.w, w1.x,w1.y,w1.z,w1.w,
                    w2.x,w2.y,w2.z,w2.w, w3.x,w3.y,w3.z,w3.w};
    #pragma unroll
    for (int i = 0; i < 16; i++){
      acc[i].x = fmaf(wv[i], xv.x, acc[i].x);
      acc[i].y = fmaf(wv[i], xv.y, acc[i].y);
    }
  }
  if (mat < 2){
    bf16* ob = outp + (size_t)b*NB;
    #pragma unroll
    for (int i = 0; i < 16; i += 2){
      __hip_bfloat162 h0 = __float22bfloat162_rn(
          make_float2(acc[i].x + Bl[i], acc[i+1].x + Bl[i+1]));
      __hip_bfloat162 h1 = __float22bfloat162_rn(
          make_float2(acc[i].y + Bl[i], acc[i+1].y + Bl[i+1]));
      *(__hip_bfloat162*)&ob[(size_t)p*64 + c0 + i]     = h0;
      *(__hip_bfloat162*)&ob[(size_t)(p+1)*64 + c0 + i] = h1;
    }
  } else {
    const size_t base = (size_t)b*NB + p;
    #pragma unroll
    for (int i = 0; i < 16; i++){
      float bl = Bl[i];
      __hip_bfloat162 o2 = __float22bfloat162_rn(make_float2(acc[i].x + bl, acc[i].y + bl));
      *(__hip_bfloat162*)&outp[base + (size_t)(c0 + i)*HW] = o2;
    }
  }
}

// ---------------- channel attention: gram row + softmax(-S) ----------------
// grid (64 c, 4 b), 256 threads
__global__ __launch_bounds__(256) void k_chan_attn(
    const float* __restrict__ fcb, float* __restrict__ attn){
  __shared__ __align__(16) float rowc[4096];
  __shared__ float red[256];
  __shared__ float Srow[64];
  const int c = blockIdx.x, b = blockIdx.y, t = threadIdx.x;
  const float* fa = fcb + (size_t)b*NB;
  #pragma unroll
  for (int i = 0; i < 4; i++){
    int n = i*1024 + t*4;
    *(float4*)&rowc[n] = *(const float4*)&fa[(size_t)c*HW + n];
  }
  __syncthreads();
  const int d = t >> 2, part = t & 3;
  const float* frow = fa + (size_t)d*HW + part*1024;
  const float* rc = rowc + part*1024;
  float s = 0.f;
  for (int i = 0; i < 1024; i += 4){
    float4 xv = *(const float4*)&frow[i];
    float4 rv = *(const float4*)&rc[i];
    s += xv.x*rv.x + xv.y*rv.y + xv.z*rv.z + xv.w*rv.w;
  }
  red[t] = s;
  __syncthreads();
  if (part == 0) Srow[d] = red[t] + red[t+1] + red[t+2] + red[t+3];
  __syncthreads();
  if (t < 64){
    float z = -Srow[t];
    float m = z;
    #pragma unroll
    for (int off = 32; off; off >>= 1) m = fmaxf(m, __shfl_xor(m, off));
    float e = __expf(fminf(z - m, 0.f));
    float ss = e;
    #pragma unroll
    for (int off = 32; off; off >>= 1) ss += __shfl_xor(ss, off);
    attn[(size_t)b*4096 + (size_t)c*64 + t] = e / ss;
  }
}

// ---------------- position attention: split-K flash, swapped-QK^T, double-buffered ----------------
// 512 threads = 8 waves = 2 groups of 4 waves. Group g owns keys [g*2048, (g+1)*2048).
// Swapped QK^T: S^T = MFMA(A=K, B=Q) so each lane owns q=lr and 32 keys; permuted
// K-row read makes the lane's keys exactly the PV B-fragment (P stays in registers).
// DOUBLE-BUFFERED LDS: stage tile t+1 into buf[nxt] while computing tile t from
// buf[cur]; ONE barrier per tile (was 2 + exposed write->read chain). Global loads
// for tile t+2 issued mid-iteration (full iteration of latency cover).
// amdgpu_waves_per_eu(2,2): grid = 256 blocks = 1 block/CU = 2 waves/EU always;
// cap allocator's occupancy target -> 256-VGPR budget, no spill (rounds 4-6 bug).
__global__ __attribute__((amdgpu_flat_work_group_size(512, 512), amdgpu_waves_per_eu(2, 2)))
void k_pos_attn(
    const u16* __restrict__ fBt, const u16* __restrict__ fCt, const u16* __restrict__ fDv,
    const float* __restrict__ fpl, const float* __restrict__ alphap,
    float* __restrict__ fus){
  __shared__ __align__(16) u16 Kt[2][2][128*72];   // [stage][group][k][c] pitch 72
  __shared__ __align__(16) u16 Vt[2][2][64*136];   // [stage][group][c][k] pitch 136

  const int t = threadIdx.x;
  const int b = blockIdx.y, q0 = blockIdx.x*64;
  const int wv = t>>6;            // 0..7
  const int g  = wv>>2;           // split-K group
  const int wg = wv&3;            // wave-in-group -> q sub-tile
  const int lane = t&63, quad = lane>>4, lr = lane&15;
  const int tg = t & 255;         // thread-in-group
  const u16* Fb = fBt + (size_t)b*NB;
  const u16* Fc = fCt + (size_t)b*NB;
  const u16* Fd = fDv + (size_t)b*NB;

  // Q B-fragments ([q][c] layout): col j = lr -> q row q0 + wg*16 + lr
  const size_t qoff = (size_t)(q0 + wg*16 + lr)*64;
  short8 a0 = *(const short8*)&Fb[qoff + quad*8];
  short8 a1 = *(const short8*)&Fb[qoff + 32 + quad*8];

  // permuted K-row base: L(ks,lr) = 32*(ks>>1) + 8*(lr>>2) + 4*(ks&1) + (lr&3)
  const int krbase = ((lr>>2)<<3) + (lr&3);

  float m = -3.0e38f, l = 0.f;
  f32x4 accO[4];
  #pragma unroll
  for (int cs = 0; cs < 4; cs++) accO[cs] = (f32x4){0.f,0.f,0.f,0.f};

  // staging indices (per group of 256 threads)
  const int skk = tg>>1, sch = (tg&1)*32;        // Kt: 128 rows x 64 ch, 64B/thread
  const int svc = tg>>2, svk = (tg&3)*32;        // Vt: 64 rows x 128 keys, 64B/thread
  const u16* Ksrc = Fc + (size_t)(g*2048 + skk)*64 + sch;
  const u16* Vsrc = Fd + (size_t)svc*HW + g*2048 + svk;
  const int kof = skk*72 + sch;
  const int vof = svc*136 + svk;

  // prologue: tile 0 -> LDS stage 0; tile 1 -> registers
  uint4 kr[4], vr[4];
  #pragma unroll
  for (int i = 0; i < 4; i++){
    kr[i] = ((const uint4*)Ksrc)[i];
    vr[i] = ((const uint4*)Vsrc)[i];
  }
  {
    u16* kd = &Kt[0][g][kof];
    u16* vd = &Vt[0][g][vof];
    #pragma unroll
    for (int i = 0; i < 4; i++) ((uint4*)kd)[i] = kr[i];
    #pragma unroll
    for (int i = 0; i < 4; i++) ((uint4*)vd)[i] = vr[i];
  }
  #pragma unroll
  for (int i = 0; i < 4; i++){
    kr[i] = ((const uint4*)(Ksrc + 128*64))[i];
    vr[i] = ((const uint4*)(Vsrc + 128))[i];
  }
  __syncthreads();   // stage 0 visible

  for (int tile = 0; tile < 16; ++tile){
    const int cur = tile & 1, nxt = cur ^ 1;

    // stage tile+1 into buf[nxt] (regs already loaded); drains under compute
    if (tile < 15){
      u16* kd = &Kt[nxt][g][kof];
      u16* vd = &Vt[nxt][g][vof];
      #pragma unroll
      for (int i = 0; i < 4; i++) ((uint4*)kd)[i] = kr[i];
      #pragma unroll
      for (int i = 0; i < 4; i++) ((uint4*)vd)[i] = vr[i];
    }
    // issue tile+2 global loads; full iteration of latency cover
    if (tile < 14){
      const u16* ks2 = Ksrc + (size_t)(tile+2)*128*64;
      const u16* vs2 = Vsrc + (tile+2)*128;
      #pragma unroll
      for (int i = 0; i < 4; i++){
        kr[i] = ((const uint4*)ks2)[i];
        vr[i] = ((const uint4*)vs2)[i];
      }
    }

    // S^T = K Q^T: lane (quad,lr) reg r of subtile ks holds
    // S[q=lr][key = 32*(ks>>1) + 8*quad + 4*(ks&1) + r]
    f32x4 s[8];
    #pragma unroll
    for (int ks = 0; ks < 8; ks++){
      const int krow = krbase + ((ks>>1)<<5) + ((ks&1)<<2);
      short8 k0 = *(short8*)&Kt[cur][g][krow*72 + quad*8];
      short8 k1 = *(short8*)&Kt[cur][g][krow*72 + 32 + quad*8];
      f32x4 acc = {0.f,0.f,0.f,0.f};
      acc = MFMA16(k0, a0, acc);
      acc = MFMA16(k1, a1, acc);
      s[ks] = acc;
    }

    // online softmax, fully in registers; lane owns one q-row (q = lr)
    float t4[8];
    #pragma unroll
    for (int ks = 0; ks < 8; ks++)
      t4[ks] = fmaxf(fmaxf(s[ks][0], s[ks][1]), fmaxf(s[ks][2], s[ks][3]));
    float mx = fmaxf(fmaxf(fmaxf(t4[0],t4[1]), fmaxf(t4[2],t4[3])),
                     fmaxf(fmaxf(t4[4],t4[5]), fmaxf(t4[6],t4[7])));
    mx = fmaxf(mx, __shfl_xor(mx, 16));
    mx = fmaxf(mx, __shfl_xor(mx, 32));
    const float mn = fmaxf(m, mx);
    const float al = __expf(m - mn);
    m = mn;

    // exp + pack to bf16 PV B-fragments via element inserts (constant lanes only)
    short8 pf0, pf1, pf2, pf3;
    float rs = 0.f;
    #pragma unroll
    for (int ks = 0; ks < 8; ks++){
      float e0 = __expf(s[ks][0] - m);
      float e1 = __expf(s[ks][1] - m);
      float e2 = __expf(s[ks][2] - m);
      float e3 = __expf(s[ks][3] - m);
      rs += (e0 + e1) + (e2 + e3);
      const int o = (ks&1)*4;
      short b0 = f2bf(e0), b1 = f2bf(e1), b2 = f2bf(e2), b3 = f2bf(e3);
      if ((ks>>1) == 0){ pf0[o]=b0; pf0[o+1]=b1; pf0[o+2]=b2; pf0[o+3]=b3; }
      else if ((ks>>1) == 1){ pf1[o]=b0; pf1[o+1]=b1; pf1[o+2]=b2; pf1[o+3]=b3; }
      else if ((ks>>1) == 2){ pf2[o]=b0; pf2[o+1]=b1; pf2[o+2]=b2; pf2[o+3]=b3; }
      else            { pf3[o]=b0; pf3[o+1]=b1; pf3[o+2]=b2; pf3[o+3]=b3; }
    }
    rs += __shfl_xor(rs, 16);
    rs += __shfl_xor(rs, 32);
    l = l*al + rs;
    #pragma unroll
    for (int cs = 0; cs < 4; cs++) accO[cs] *= al;

    // O^T += V P^T : A = V[c][k] from LDS, B = P from registers
    #pragma unroll
    for (int cs = 0; cs < 4; cs++){
      short8 vf0 = *(short8*)&Vt[cur][g][(cs*16+lr)*136 +  0 + quad*8];
      short8 vf1 = *(short8*)&Vt[cur][g][(cs*16+lr)*136 + 32 + quad*8];
      short8 vf2 = *(short8*)&Vt[cur][g][(cs*16+lr)*136 + 64 + quad*8];
      short8 vf3 = *(short8*)&Vt[cur][g][(cs*16+lr)*136 + 96 + quad*8];
      accO[cs] = MFMA16(vf0, pf0, accO[cs]);
      accO[cs] = MFMA16(vf1, pf1, accO[cs]);
      accO[cs] = MFMA16(vf2, pf2, accO[cs]);
      accO[cs] = MFMA16(vf3, pf3, accO[cs]);
    }

    __syncthreads();   // buf[nxt] writes visible; buf[cur] reads done
  }
  // lane (quad,lr) reg r of accO[cs]: O^T[c = 16cs+4quad+r][q = wg*16+lr]

  // ---- flash-combine of the 2 groups' partials, in LDS (aliases Kt) ----
  float* Ol = (float*)&Kt[0][0][0];   // 64 x pitch-69 f32 (18432+ B available)
  float* Ml = Ol + 64*69;
  float* Ll = Ml + 64;
  if (g == 1){
    const int row = wg*16 + lr;
    #pragma unroll
    for (int cs = 0; cs < 4; cs++){
      #pragma unroll
      for (int r = 0; r < 4; r++)
        Ol[row*69 + cs*16 + quad*4 + r] = accO[cs][r];
    }
    if (quad == 0){ Ml[row] = m; Ll[row] = l; }
  }
  __syncthreads();
  if (g == 0){
    const float alp = alphap[0];
    const int row = wg*16 + lr;
    const float m1 = Ml[row], l1 = Ll[row];
    const float mt = fmaxf(m, m1);
    const float e0 = __expf(m - mt), e1 = __expf(m1 - mt);
    const float lt = fmaxf(l*e0 + l1*e1, 1e-20f);
    const float sc = alp / lt;
    #pragma unroll
    for (int cs = 0; cs < 4; cs++){
      #pragma unroll
      for (int r = 0; r < 4; r++){
        int idx = row*69 + cs*16 + quad*4 + r;
        Ol[idx] = (accO[cs][r]*e0 + Ol[idx]*e1) * sc;  // lane-local RAW across barrier
      }
    }
  }
  __syncthreads();

  // ---- coalesced epilogue: fus[c][q] = Ol[q][c] + fp[c][q] ----
  {
    const int c = t >> 3, qs = (t & 7) * 8;
    const float* Fp = fpl + (size_t)b*NB + (size_t)c*HW + q0 + qs;
    float* Fo = fus + (size_t)b*NB + (size_t)c*HW + q0 + qs;
    float v[8];
    #pragma unroll
    for (int j = 0; j < 8; j++) v[j] = Ol[(qs+j)*69 + c] + Fp[j];
    *(float4*)&Fo[0] = make_float4(v[0],v[1],v[2],v[3]);
    *(float4*)&Fo[4] = make_float4(v[4],v[5],v[6],v[7]);
  }
}

// ---------------- channel apply: fus += beta*(attn@fa) + fcb ----------------
// grid (16 ptiles of 256, 8 cgroups of 8, 4 b)
__global__ __launch_bounds__(256) void k_chan_apply(
    const float* __restrict__ fcb, const float* __restrict__ attn,
    const float* __restrict__ betap, float* __restrict__ fus){
  __shared__ __align__(16) float Ar2[64][8];
  const int t = threadIdx.x;
  const int c0 = blockIdx.y*8, b = blockIdx.z;
  for (int i = t; i < 512; i += 256){
    int d = i >> 3, ci = i & 7;
    Ar2[d][ci] = attn[(size_t)b*4096 + (size_t)(c0 + ci)*64 + d];
  }
  __syncthreads();
  const int p = blockIdx.x*256 + t;
  const float* fa = fcb + (size_t)b*NB;
  float acc[8] = {0.f,0.f,0.f,0.f,0.f,0.f,0.f,0.f};
  for (int d = 0; d < 64; d++){
    float v = fa[(size_t)d*HW + p];
    float4 A0 = *(const float4*)&Ar2[d][0];
    float4 A1 = *(const float4*)&Ar2[d][4];
    acc[0]=fmaf(A0.x,v,acc[0]); acc[1]=fmaf(A0.y,v,acc[1]); acc[2]=fmaf(A0.z,v,acc[2]); acc[3]=fmaf(A0.w,v,acc[3]);
    acc[4]=fmaf(A1.x,v,acc[4]); acc[5]=fmaf(A1.y,v,acc[5]); acc[6]=fmaf(A1.z,v,acc[6]); acc[7]=fmaf(A1.w,v,acc[7]);
  }
  const float be = betap[0];
  #pragma unroll
  for (int i = 0; i < 8; i++){
    size_t idx = (size_t)b*NB + (size_t)(c0 + i)*HW + p;
    fus[idx] += fmaf(be, acc[i], fa[(size_t)(c0 + i)*HW + p]);
  }
}

// ---------------- out conv (64 -> 512) + BN, fp32 out, LDS weights ----------------
// grid (8 ptiles of 512, 32 ogroups of 16, 4 b)
__global__ __launch_bounds__(256) void k_conv_out(
    const float* __restrict__ fus, const float* __restrict__ wo,
    const float* __restrict__ bn, float* __restrict__ out){
  __shared__ __align__(16) float Wl[64][16];
  const int t = threadIdx.x;
  const int o0 = blockIdx.y*16, b = blockIdx.z;
  for (int i = t; i < 1024; i += 256){
    int o = i & 15, c = i >> 4;
    Wl[c][o] = wo[(size_t)(o0 + o)*64 + c];
  }
  __syncthreads();
  const int p = blockIdx.x*512 + t*2;
  const float* fu = fus + (size_t)b*NB + p;
  float2 acc[16];
  #pragma unroll
  for (int i = 0; i < 16; i++){ acc[i].x = 0.f; acc[i].y = 0.f; }
  for (int c = 0; c < 64; c++){
    float2 xv = *(const float2*)(fu + (size_t)c*HW);
    float4 w0 = *(const float4*)&Wl[c][0];
    float4 w1 = *(const float4*)&Wl[c][4];
    float4 w2 = *(const float4*)&Wl[c][8];
    float4 w3 = *(const float4*)&Wl[c][12];
    float wv[16] = {w0.x,w0.y,w0.z,w0.w, w1.x,w1.y,w1.z,w1.w,
                    w2.x,w2.y,w2.z,w2.w, w3.x,w3.y,w3.z,w3.w};
    #pragma unroll
    for (int i = 0; i < 16; i++){
      acc[i].x = fmaf(wv[i], xv.x, acc[i].x);
      acc[i].y = fmaf(wv[i], xv.y, acc[i].y);
    }
  }
  #pragma unroll
  for (int i = 0; i < 16; i++){
    int o = o0 + i;
    float iv = bn[256+o], bs = bn[768+o];
    float* op = &out[(size_t)b*512*HW + (size_t)o*HW + p];
    op[0] = fmaf(acc[i].x, iv, bs);
    op[1] = fmaf(acc[i].y, iv, bs);
  }
}

extern "C" void kernel_launch(void* const* d_in, const int* in_sizes, int n_in,
                              void* d_out, int out_size, void* d_ws, size_t ws_size,
                              hipStream_t stream){
  static const int dictSz[24] = {8388608,32768,64,64,64,64,32768,64,64,64,64,
                                 4096,64,4096,64,4096,64,1,1,32768,512,512,512,512};
  bool dictOk = (n_in == 24);
  if (dictOk){
    for (int i = 0; i < 24; i++) if (in_sizes[i] != dictSz[i]) dictOk = false;
  }
  bool wsOk = (ws_size >= (size_t)(19u << 20));
  float* out = (float*)d_out;
  if (!dictOk){ k_const<<<(out_size+255)/256, 256, 0, stream>>>(out, 32.f, out_size); return; }
  if (!wsOk)  { k_const<<<(out_size+255)/256, 256, 0, stream>>>(out, 48.f, out_size); return; }

  const float* x    = (const float*)d_in[0];
  const float* wp1  = (const float*)d_in[1];
  const float* gp1  = (const float*)d_in[2];  const float* bp1 = (const float*)d_in[3];
  const float* mp1  = (const float*)d_in[4];  const float* vp1 = (const float*)d_in[5];
  const float* wc1  = (const float*)d_in[6];
  const float* gc1  = (const float*)d_in[7];  const float* bc1 = (const float*)d_in[8];
  const float* mc1  = (const float*)d_in[9];  const float* vc1 = (const float*)d_in[10];
  const float* wb   = (const float*)d_in[11]; const float* bb  = (const float*)d_in[12];
  const float* wc2  = (const float*)d_in[13]; const float* bc2 = (const float*)d_in[14];
  const float* wd   = (const float*)d_in[15]; const float* bd  = (const float*)d_in[16];
  const float* alp  = (const float*)d_in[17]; const float* bet = (const float*)d_in[18];
  const float* wo   = (const float*)d_in[19];
  const float* go   = (const float*)d_in[20]; const float* bo  = (const float*)d_in[21];
  const float* mo   = (const float*)d_in[22]; const float* vo  = (const float*)d_in[23];

  char* w8 = (char*)d_ws;
  float* fp    = (float*)(w8);
  float* fcb   = (float*)(w8 + (4u<<20));
  float* fus   = (float*)(w8 + (8u<<20));
  bf16*  fB    = (bf16*) (w8 + (12u<<20));   // [q][c]
  bf16*  fC    = (bf16*) (w8 + (14u<<20));   // [k][c]
  bf16*  fD    = (bf16*) (w8 + (16u<<20));   // [c][k]
  float* attnc = (float*)(w8 + (18u<<20));
  float* bn    = (float*)(w8 + (18u<<20) + 65536);

  k_prep<<<1, 512, 0, stream>>>(gp1,bp1,mp1,vp1, gc1,bc1,mc1,vc1, go,bo,mo,vo, bn);
  k_conv_in<<<dim3(16,8,4), 256, 0, stream>>>(x, wp1, wc1, bn, fp, fcb);
  k_qkv<<<dim3(8,12,4), 256, 0, stream>>>(fp, wb,bb, wc2,bc2, wd,bd, fB, fC, fD);
  k_chan_attn<<<dim3(64,4), 256, 0, stream>>>(fcb, attnc);
  k_pos_attn<<<dim3(64,4), 512, 0, stream>>>((const u16*)fB, (const u16*)fC, (const u16*)fD,
                                             fp, alp, fus);
  k_chan_apply<<<dim3(16,8,4), 256, 0, stream>>>(fcb, attnc, bet, fus);
  k_conv_out<<<dim3(8,32,4), 256, 0, stream>>>(fus, wo, bn, out);
}

// Round 9
// 334.690 us; speedup vs baseline: 1.0285x; 1.0285x over previous
//
#include <hip/hip_runtime.h>
#include <hip/hip_bf16.h>

typedef __hip_bfloat16 bf16;
typedef unsigned short u16;
typedef __attribute__((ext_vector_type(8))) short short8;
typedef __attribute__((ext_vector_type(4))) float f32x4;

#define HW 4096
#define NB (64*HW)

__device__ __forceinline__ f32x4 MFMA16(short8 a, short8 b, f32x4 c){
  return __builtin_amdgcn_mfma_f32_16x16x32_bf16(a, b, c, 0, 0, 0);
}

__device__ __forceinline__ short f2bf(float f){
  bf16 h = __float2bfloat16(f);
  return *(short*)&h;          // scalar pun — promoted to register (round-0 verified)
}

// diagnostic fill (fp32 output)
__global__ __launch_bounds__(256) void k_const(float* __restrict__ out, float v, int n){
  int i = blockIdx.x*256 + threadIdx.x;
  if (i < n) out[i] = v;
}

// ---------------- BN fold ----------------
// bn: [0,64) invp | [64,128) biasp | [128,192) invc | [192,256) biasc | [256,768) invo | [768,1280) biaso
__global__ __launch_bounds__(512) void k_prep(
    const float* __restrict__ gp, const float* __restrict__ bp,
    const float* __restrict__ mp, const float* __restrict__ vp,
    const float* __restrict__ gc, const float* __restrict__ bc,
    const float* __restrict__ mc, const float* __restrict__ vc,
    const float* __restrict__ go, const float* __restrict__ bo,
    const float* __restrict__ mo, const float* __restrict__ vo,
    float* __restrict__ bn){
  int t = threadIdx.x;
  if (t < 64){
    float iv = gp[t] * rsqrtf(vp[t] + 1e-5f);
    bn[t] = iv; bn[64+t] = bp[t] - mp[t]*iv;
    float ic = gc[t] * rsqrtf(vc[t] + 1e-5f);
    bn[128+t] = ic; bn[192+t] = bc[t] - mc[t]*ic;
  }
  float io = go[t] * rsqrtf(vo[t] + 1e-5f);
  bn[256+t] = io; bn[768+t] = bo[t] - mo[t]*io;
}

// ---------------- conv_in: 512->64 x2, BN folded, LDS weights ----------------
// grid (16 ptiles of 256 px, 8 cgroups, 4 b); cg<4 -> fp(wp1), cg>=4 -> fcb(wc1)
__global__ __launch_bounds__(256) void k_conv_in(
    const float* __restrict__ x, const float* __restrict__ wp1, const float* __restrict__ wc1,
    const float* __restrict__ bn, float* __restrict__ fp, float* __restrict__ fcb){
  __shared__ __align__(16) float Wl[512][16];
  const int t = threadIdx.x;
  const int cg = blockIdx.y, b = blockIdx.z;
  const bool isP = cg < 4;
  const int c0 = (cg & 3) * 16;
  const float* w = isP ? wp1 : wc1;
  const float* inv  = isP ? bn       : bn + 128;
  const float* bias = isP ? bn + 64  : bn + 192;
  float* outp = isP ? fp : fcb;
  for (int i = t; i < 8192; i += 256){
    int c = i & 15, k = i >> 4;
    Wl[k][c] = w[(size_t)(c0 + c)*512 + k];
  }
  __syncthreads();
  const int p = blockIdx.x*256 + t;
  const float* xb = x + (size_t)b*512*HW + p;
  float acc[16];
  #pragma unroll
  for (int i = 0; i < 16; i++) acc[i] = 0.f;
  for (int k = 0; k < 512; k++){
    float xv = xb[(size_t)k*HW];
    float4 w0 = *(const float4*)&Wl[k][0];
    float4 w1 = *(const float4*)&Wl[k][4];
    float4 w2 = *(const float4*)&Wl[k][8];
    float4 w3 = *(const float4*)&Wl[k][12];
    acc[0]=fmaf(w0.x,xv,acc[0]); acc[1]=fmaf(w0.y,xv,acc[1]); acc[2]=fmaf(w0.z,xv,acc[2]); acc[3]=fmaf(w0.w,xv,acc[3]);
    acc[4]=fmaf(w1.x,xv,acc[4]); acc[5]=fmaf(w1.y,xv,acc[5]); acc[6]=fmaf(w1.z,xv,acc[6]); acc[7]=fmaf(w1.w,xv,acc[7]);
    acc[8]=fmaf(w2.x,xv,acc[8]); acc[9]=fmaf(w2.y,xv,acc[9]); acc[10]=fmaf(w2.z,xv,acc[10]); acc[11]=fmaf(w2.w,xv,acc[11]);
    acc[12]=fmaf(w3.x,xv,acc[12]); acc[13]=fmaf(w3.y,xv,acc[13]); acc[14]=fmaf(w3.z,xv,acc[14]); acc[15]=fmaf(w3.w,xv,acc[15]);
  }
  const size_t base = (size_t)b*NB + p;
  #pragma unroll
  for (int i = 0; i < 16; i++){
    int c = c0 + i;
    outp[base + (size_t)c*HW] = fmaf(acc[i], inv[c], bias[c]);
  }
}

// ---------------- QKV convs; Q,K transposed [p][c], V natural [c][p] ----------------
// grid (8 ptiles of 512, 12 = 3 mats * 4 cgroups, 4 b)
__global__ __launch_bounds__(256) void k_qkv(
    const float* __restrict__ fp,
    const float* __restrict__ wb,  const float* __restrict__ bbv,
    const float* __restrict__ wc2, const float* __restrict__ bc2,
    const float* __restrict__ wd,  const float* __restrict__ bd,
    bf16* __restrict__ fB, bf16* __restrict__ fC, bf16* __restrict__ fD){
  __shared__ __align__(16) float Wl[64][16];
  __shared__ float Bl[16];
  const int t = threadIdx.x;
  const int mg = blockIdx.y, mat = mg >> 2, c0 = (mg & 3)*16, b = blockIdx.z;
  const float* w    = (mat == 0) ? wb  : (mat == 1 ? wc2 : wd);
  const float* bias = (mat == 0) ? bbv : (mat == 1 ? bc2 : bd);
  bf16* outp        = (mat == 0) ? fB  : (mat == 1 ? fC  : fD);
  for (int i = t; i < 1024; i += 256){
    int c = i & 15, k = i >> 4;
    Wl[k][c] = w[(size_t)(c0 + c)*64 + k];
  }
  if (t < 16) Bl[t] = bias[c0 + t];
  __syncthreads();
  const int p = blockIdx.x*512 + t*2;
  const float* in = fp + (size_t)b*NB + p;
  float2 acc[16];
  #pragma unroll
  for (int i = 0; i < 16; i++){ acc[i].x = 0.f; acc[i].y = 0.f; }
  for (int k = 0; k < 64; k++){
    float2 xv = *(const float2*)(in + (size_t)k*HW);
    float4 w0 = *(const float4*)&Wl[k][0];
    float4 w1 = *(const float4*)&Wl[k][4];
    float4 w2 = *(const float4*)&Wl[k][8];
    float4 w3 = *(const float4*)&Wl[k][12];
    float wv[16] = {w0.x,w0.y,w0.z,w0.w, w1.x,w1.y,w1.z,w1.w,
                    w2.x,w2.y,w2.z,w2.w, w3.x,w3.y,w3.z,w3.w};
    #pragma unroll
    for (int i = 0; i < 16; i++){
      acc[i].x = fmaf(wv[i], xv.x, acc[i].x);
      acc[i].y = fmaf(wv[i], xv.y, acc[i].y);
    }
  }
  if (mat < 2){
    bf16* ob = outp + (size_t)b*NB;
    #pragma unroll
    for (int i = 0; i < 16; i += 2){
      __hip_bfloat162 h0 = __float22bfloat162_rn(
          make_float2(acc[i].x + Bl[i], acc[i+1].x + Bl[i+1]));
      __hip_bfloat162 h1 = __float22bfloat162_rn(
          make_float2(acc[i].y + Bl[i], acc[i+1].y + Bl[i+1]));
      *(__hip_bfloat162*)&ob[(size_t)p*64 + c0 + i]     = h0;
      *(__hip_bfloat162*)&ob[(size_t)(p+1)*64 + c0 + i] = h1;
    }
  } else {
    const size_t base = (size_t)b*NB + p;
    #pragma unroll
    for (int i = 0; i < 16; i++){
      float bl = Bl[i];
      __hip_bfloat162 o2 = __float22bfloat162_rn(make_float2(acc[i].x + bl, acc[i].y + bl));
      *(__hip_bfloat162*)&outp[base + (size_t)(c0 + i)*HW] = o2;
    }
  }
}

// ---------------- channel attention: gram row + softmax(-S) ----------------
// grid (64 c, 4 b), 256 threads
__global__ __launch_bounds__(256) void k_chan_attn(
    const float* __restrict__ fcb, float* __restrict__ attn){
  __shared__ __align__(16) float rowc[4096];
  __shared__ float red[256];
  __shared__ float Srow[64];
  const int c = blockIdx.x, b = blockIdx.y, t = threadIdx.x;
  const float* fa = fcb + (size_t)b*NB;
  #pragma unroll
  for (int i = 0; i < 4; i++){
    int n = i*1024 + t*4;
    *(float4*)&rowc[n] = *(const float4*)&fa[(size_t)c*HW + n];
  }
  __syncthreads();
  const int d = t >> 2, part = t & 3;
  const float* frow = fa + (size_t)d*HW + part*1024;
  const float* rc = rowc + part*1024;
  float s = 0.f;
  for (int i = 0; i < 1024; i += 4){
    float4 xv = *(const float4*)&frow[i];
    float4 rv = *(const float4*)&rc[i];
    s += xv.x*rv.x + xv.y*rv.y + xv.z*rv.z + xv.w*rv.w;
  }
  red[t] = s;
  __syncthreads();
  if (part == 0) Srow[d] = red[t] + red[t+1] + red[t+2] + red[t+3];
  __syncthreads();
  if (t < 64){
    float z = -Srow[t];
    float m = z;
    #pragma unroll
    for (int off = 32; off; off >>= 1) m = fmaxf(m, __shfl_xor(m, off));
    float e = __expf(fminf(z - m, 0.f));
    float ss = e;
    #pragma unroll
    for (int off = 32; off; off >>= 1) ss += __shfl_xor(ss, off);
    attn[(size_t)b*4096 + (size_t)c*64 + t] = e / ss;
  }
}

// ---------------- position attention: in-block split-K flash, swapped-QK^T ----------------
// 512 threads = 8 waves = 2 groups of 4 waves. Group g owns keys [g*2048, (g+1)*2048).
// Swapped QK^T: S^T = MFMA(A=K, B=Q) so each lane owns q=lr and 32 keys.
// Permuted K-row read L(ks,lr) makes the lane's owned keys exactly the PV
// B-fragment {32kc+8*quad .. +7}: P never touches LDS (no Pt, one less barrier).
// Kt SLOT SWIZZLE: phys_16B_slot = (logical + 2*((row>>3)&3)) & 7 on write+read.
// QK read was 4-way bank-conflicted (start bank 4(b+quad), only 4 of 8 starts);
// swizzled start = (8u+4v)%32 -> every start bank hit exactly 2x = free (m136).
// amdgpu_waves_per_eu(2,2): grid = 256 blocks = 1 block/CU = 2 waves/EU always;
// cap allocator's occupancy target -> no scratch spill (rounds 4-6/8 bug; R8's
// dbuf raised live ranges and re-spilled, so stay with this 2-barrier structure).
__global__ __attribute__((amdgpu_flat_work_group_size(512, 512), amdgpu_waves_per_eu(2, 2)))
void k_pos_attn(
    const u16* __restrict__ fBt, const u16* __restrict__ fCt, const u16* __restrict__ fDv,
    const float* __restrict__ fpl, const float* __restrict__ alphap,
    float* __restrict__ fus){
  __shared__ __align__(16) u16 Kt[2][128*72];   // [k][c] pitch 72, per group (slot-swizzled)
  __shared__ __align__(16) u16 Vt[2][64*136];   // [c][k] pitch 136, per group

  const int t = threadIdx.x;
  const int b = blockIdx.y, q0 = blockIdx.x*64;
  const int wv = t>>6;            // 0..7
  const int g  = wv>>2;           // split-K group
  const int wg = wv&3;            // wave-in-group -> q sub-tile
  const int lane = t&63, quad = lane>>4, lr = lane&15;
  const int tg = t & 255;         // thread-in-group
  const u16* Fb = fBt + (size_t)b*NB;
  const u16* Fc = fCt + (size_t)b*NB;
  const u16* Fd = fDv + (size_t)b*NB;

  // Q B-fragments ([q][c] layout): col j = lr -> q row q0 + wg*16 + lr
  const size_t qoff = (size_t)(q0 + wg*16 + lr)*64;
  short8 a0 = *(const short8*)&Fb[qoff + quad*8];
  short8 a1 = *(const short8*)&Fb[qoff + 32 + quad*8];

  // permuted K-row base: L(ks,lr) = 32*(ks>>1) + 8*(lr>>2) + 4*(ks&1) + (lr&3)
  const int krbase = ((lr>>2)<<3) + (lr&3);

  float m = -3.0e38f, l = 0.f;
  f32x4 accO[4];
  #pragma unroll
  for (int cs = 0; cs < 4; cs++) accO[cs] = (f32x4){0.f,0.f,0.f,0.f};

  // staging indices (per group of 256 threads)
  const int skk = tg>>1, sch = (tg&1)*32;        // Kt: 128 rows x 64 ch, 64B/thread
  const int svc = tg>>2, svk = (tg&3)*32;        // Vt: 64 rows x 128 keys, 64B/thread
  const u16* Ksrc = Fc + (size_t)(g*2048 + skk)*64 + sch;
  const u16* Vsrc = Fd + (size_t)svc*HW + g*2048 + svk;
  const int ksb = (tg&1)*4;                       // K logical slot base (16B units)
  const int ksw = ((skk>>3)&3)*2;                 // K row swizzle term

  // prologue: prefetch tile 0 into registers
  uint4 kr[4], vr[4];
  #pragma unroll
  for (int i = 0; i < 4; i++){
    kr[i] = ((const uint4*)Ksrc)[i];
    vr[i] = ((const uint4*)Vsrc)[i];
  }

  for (int tile = 0; tile < 16; ++tile){
    __syncthreads();   // prev iteration consumed Kt/Vt
    {
      u16* krow0 = &Kt[g][skk*72];
      #pragma unroll
      for (int i = 0; i < 4; i++)
        *(uint4*)&krow0[((ksb + i + ksw) & 7) * 8] = kr[i];
      u16* vd = &Vt[g][svc*136 + svk];
      #pragma unroll
      for (int i = 0; i < 4; i++) ((uint4*)vd)[i] = vr[i];
    }
    __syncthreads();   // staged tile visible

    // issue next tile's global loads now; latency hides under QK+softmax+PV
    if (tile < 15){
      const u16* ks2 = Ksrc + (size_t)(tile+1)*128*64;
      const u16* vs2 = Vsrc + (tile+1)*128;
      #pragma unroll
      for (int i = 0; i < 4; i++){
        kr[i] = ((const uint4*)ks2)[i];
        vr[i] = ((const uint4*)vs2)[i];
      }
    }

    // S^T = K Q^T: lane (quad,lr) reg r of subtile ks holds
    // S[q=lr][key = 32*(ks>>1) + 8*quad + 4*(ks&1) + r]
    f32x4 s[8];
    #pragma unroll
    for (int ks = 0; ks < 8; ks++){
      const int krow = krbase + ((ks>>1)<<5) + ((ks&1)<<2);
      const int sw = ((krow>>3)&3)*2;
      short8 k0 = *(short8*)&Kt[g][krow*72 + ((quad + sw) & 7)*8];
      short8 k1 = *(short8*)&Kt[g][krow*72 + ((quad + 4 + sw) & 7)*8];
      f32x4 acc = {0.f,0.f,0.f,0.f};
      acc = MFMA16(k0, a0, acc);
      acc = MFMA16(k1, a1, acc);
      s[ks] = acc;
    }

    // online softmax, fully in registers; lane owns one q-row (q = lr)
    float t4[8];
    #pragma unroll
    for (int ks = 0; ks < 8; ks++)
      t4[ks] = fmaxf(fmaxf(s[ks][0], s[ks][1]), fmaxf(s[ks][2], s[ks][3]));
    float mx = fmaxf(fmaxf(fmaxf(t4[0],t4[1]), fmaxf(t4[2],t4[3])),
                     fmaxf(fmaxf(t4[4],t4[5]), fmaxf(t4[6],t4[7])));
    mx = fmaxf(mx, __shfl_xor(mx, 16));
    mx = fmaxf(mx, __shfl_xor(mx, 32));
    const float mn = fmaxf(m, mx);
    const float al = __expf(m - mn);
    m = mn;

    // exp + pack to bf16 PV B-fragments via element inserts (constant lanes only)
    short8 pf0, pf1, pf2, pf3;
    float rs = 0.f;
    #pragma unroll
    for (int ks = 0; ks < 8; ks++){
      float e0 = __expf(s[ks][0] - m);
      float e1 = __expf(s[ks][1] - m);
      float e2 = __expf(s[ks][2] - m);
      float e3 = __expf(s[ks][3] - m);
      rs += (e0 + e1) + (e2 + e3);
      const int o = (ks&1)*4;
      short b0 = f2bf(e0), b1 = f2bf(e1), b2 = f2bf(e2), b3 = f2bf(e3);
      if ((ks>>1) == 0){ pf0[o]=b0; pf0[o+1]=b1; pf0[o+2]=b2; pf0[o+3]=b3; }
      else if ((ks>>1) == 1){ pf1[o]=b0; pf1[o+1]=b1; pf1[o+2]=b2; pf1[o+3]=b3; }
      else if ((ks>>1) == 2){ pf2[o]=b0; pf2[o+1]=b1; pf2[o+2]=b2; pf2[o+3]=b3; }
      else            { pf3[o]=b0; pf3[o+1]=b1; pf3[o+2]=b2; pf3[o+3]=b3; }
    }
    rs += __shfl_xor(rs, 16);
    rs += __shfl_xor(rs, 32);
    l = l*al + rs;
    #pragma unroll
    for (int cs = 0; cs < 4; cs++) accO[cs] *= al;

    // O^T += V P^T : A = V[c][k] from LDS, B = P from registers
    #pragma unroll
    for (int cs = 0; cs < 4; cs++){
      short8 vf0 = *(short8*)&Vt[g][(cs*16+lr)*136 +  0 + quad*8];
      short8 vf1 = *(short8*)&Vt[g][(cs*16+lr)*136 + 32 + quad*8];
      short8 vf2 = *(short8*)&Vt[g][(cs*16+lr)*136 + 64 + quad*8];
      short8 vf3 = *(short8*)&Vt[g][(cs*16+lr)*136 + 96 + quad*8];
      accO[cs] = MFMA16(vf0, pf0, accO[cs]);
      accO[cs] = MFMA16(vf1, pf1, accO[cs]);
      accO[cs] = MFMA16(vf2, pf2, accO[cs]);
      accO[cs] = MFMA16(vf3, pf3, accO[cs]);
    }
  }
  // lane (quad,lr) reg r of accO[cs]: O^T[c = 16cs+4quad+r][q = wg*16+lr]

  // ---- flash-combine of the 2 groups' partials, in LDS (aliases Kt) ----
  __syncthreads();   // both groups' PV done; Kt free for reuse
  float* Ol = (float*)&Kt[0][0];      // 64 x pitch-69 f32 (18176 B <= 18432 B)
  float* Ml = Ol + 64*69;
  float* Ll = Ml + 64;
  if (g == 1){
    const int row = wg*16 + lr;
    #pragma unroll
    for (int cs = 0; cs < 4; cs++){
      #pragma unroll
      for (int r = 0; r < 4; r++)
        Ol[row*69 + cs*16 + quad*4 + r] = accO[cs][r];
    }
    if (quad == 0){ Ml[row] = m; Ll[row] = l; }
  }
  __syncthreads();
  if (g == 0){
    const float alp = alphap[0];
    const int row = wg*16 + lr;
    const float m1 = Ml[row], l1 = Ll[row];
    const float mt = fmaxf(m, m1);
    const float e0 = __expf(m - mt), e1 = __expf(m1 - mt);
    const float lt = fmaxf(l*e0 + l1*e1, 1e-20f);
    const float sc = alp / lt;
    #pragma unroll
    for (int cs = 0; cs < 4; cs++){
      #pragma unroll
      for (int r = 0; r < 4; r++){
        int idx = row*69 + cs*16 + quad*4 + r;
        Ol[idx] = (accO[cs][r]*e0 + Ol[idx]*e1) * sc;  // lane-local RAW across barrier
      }
    }
  }
  __syncthreads();

  // ---- coalesced epilogue: fus[c][q] = Ol[q][c] + fp[c][q] ----
  {
    const int c = t >> 3, qs = (t & 7) * 8;
    const float* Fp = fpl + (size_t)b*NB + (size_t)c*HW + q0 + qs;
    float* Fo = fus + (size_t)b*NB + (size_t)c*HW + q0 + qs;
    float v[8];
    #pragma unroll
    for (int j = 0; j < 8; j++) v[j] = Ol[(qs+j)*69 + c] + Fp[j];
    *(float4*)&Fo[0] = make_float4(v[0],v[1],v[2],v[3]);
    *(float4*)&Fo[4] = make_float4(v[4],v[5],v[6],v[7]);
  }
}

// ---------------- channel apply: fus += beta*(attn@fa) + fcb ----------------
// grid (16 ptiles of 256, 8 cgroups of 8, 4 b)
__global__ __launch_bounds__(256) void k_chan_apply(
    const float* __restrict__ fcb, const float* __restrict__ attn,
    const float* __restrict__ betap, float* __restrict__ fus){
  __shared__ __align__(16) float Ar2[64][8];
  const int t = threadIdx.x;
  const int c0 = blockIdx.y*8, b = blockIdx.z;
  for (int i = t; i < 512; i += 256){
    int d = i >> 3, ci = i & 7;
    Ar2[d][ci] = attn[(size_t)b*4096 + (size_t)(c0 + ci)*64 + d];
  }
  __syncthreads();
  const int p = blockIdx.x*256 + t;
  const float* fa = fcb + (size_t)b*NB;
  float acc[8] = {0.f,0.f,0.f,0.f,0.f,0.f,0.f,0.f};
  for (int d = 0; d < 64; d++){
    float v = fa[(size_t)d*HW + p];
    float4 A0 = *(const float4*)&Ar2[d][0];
    float4 A1 = *(const float4*)&Ar2[d][4];
    acc[0]=fmaf(A0.x,v,acc[0]); acc[1]=fmaf(A0.y,v,acc[1]); acc[2]=fmaf(A0.z,v,acc[2]); acc[3]=fmaf(A0.w,v,acc[3]);
    acc[4]=fmaf(A1.x,v,acc[4]); acc[5]=fmaf(A1.y,v,acc[5]); acc[6]=fmaf(A1.z,v,acc[6]); acc[7]=fmaf(A1.w,v,acc[7]);
  }
  const float be = betap[0];
  #pragma unroll
  for (int i = 0; i < 8; i++){
    size_t idx = (size_t)b*NB + (size_t)(c0 + i)*HW + p;
    fus[idx] += fmaf(be, acc[i], fa[(size_t)(c0 + i)*HW + p]);
  }
}

// ---------------- out conv (64 -> 512) + BN, fp32 out, LDS weights ----------------
// grid (8 ptiles of 512, 32 ogroups of 16, 4 b)
__global__ __launch_bounds__(256) void k_conv_out(
    const float* __restrict__ fus, const float* __restrict__ wo,
    const float* __restrict__ bn, float* __restrict__ out){
  __shared__ __align__(16) float Wl[64][16];
  const int t = threadIdx.x;
  const int o0 = blockIdx.y*16, b = blockIdx.z;
  for (int i = t; i < 1024; i += 256){
    int o = i & 15, c = i >> 4;
    Wl[c][o] = wo[(size_t)(o0 + o)*64 + c];
  }
  __syncthreads();
  const int p = blockIdx.x*512 + t*2;
  const float* fu = fus + (size_t)b*NB + p;
  float2 acc[16];
  #pragma unroll
  for (int i = 0; i < 16; i++){ acc[i].x = 0.f; acc[i].y = 0.f; }
  for (int c = 0; c < 64; c++){
    float2 xv = *(const float2*)(fu + (size_t)c*HW);
    float4 w0 = *(const float4*)&Wl[c][0];
    float4 w1 = *(const float4*)&Wl[c][4];
    float4 w2 = *(const float4*)&Wl[c][8];
    float4 w3 = *(const float4*)&Wl[c][12];
    float wv[16] = {w0.x,w0.y,w0.z,w0.w, w1.x,w1.y,w1.z,w1.w,
                    w2.x,w2.y,w2.z,w2.w, w3.x,w3.y,w3.z,w3.w};
    #pragma unroll
    for (int i = 0; i < 16; i++){
      acc[i].x = fmaf(wv[i], xv.x, acc[i].x);
      acc[i].y = fmaf(wv[i], xv.y, acc[i].y);
    }
  }
  #pragma unroll
  for (int i = 0; i < 16; i++){
    int o = o0 + i;
    float iv = bn[256+o], bs = bn[768+o];
    float* op = &out[(size_t)b*512*HW + (size_t)o*HW + p];
    op[0] = fmaf(acc[i].x, iv, bs);
    op[1] = fmaf(acc[i].y, iv, bs);
  }
}

extern "C" void kernel_launch(void* const* d_in, const int* in_sizes, int n_in,
                              void* d_out, int out_size, void* d_ws, size_t ws_size,
                              hipStream_t stream){
  static const int dictSz[24] = {8388608,32768,64,64,64,64,32768,64,64,64,64,
                                 4096,64,4096,64,4096,64,1,1,32768,512,512,512,512};
  bool dictOk = (n_in == 24);
  if (dictOk){
    for (int i = 0; i < 24; i++) if (in_sizes[i] != dictSz[i]) dictOk = false;
  }
  bool wsOk = (ws_size >= (size_t)(19u << 20));
  float* out = (float*)d_out;
  if (!dictOk){ k_const<<<(out_size+255)/256, 256, 0, stream>>>(out, 32.f, out_size); return; }
  if (!wsOk)  { k_const<<<(out_size+255)/256, 256, 0, stream>>>(out, 48.f, out_size); return; }

  const float* x    = (const float*)d_in[0];
  const float* wp1  = (const float*)d_in[1];
  const float* gp1  = (const float*)d_in[2];  const float* bp1 = (const float*)d_in[3];
  const float* mp1  = (const float*)d_in[4];  const float* vp1 = (const float*)d_in[5];
  const float* wc1  = (const float*)d_in[6];
  const float* gc1  = (const float*)d_in[7];  const float* bc1 = (const float*)d_in[8];
  const float* mc1  = (const float*)d_in[9];  const float* vc1 = (const float*)d_in[10];
  const float* wb   = (const float*)d_in[11]; const float* bb  = (const float*)d_in[12];
  const float* wc2  = (const float*)d_in[13]; const float* bc2 = (const float*)d_in[14];
  const float* wd   = (const float*)d_in[15]; const float* bd  = (const float*)d_in[16];
  const float* alp  = (const float*)d_in[17]; const float* bet = (const float*)d_in[18];
  const float* wo   = (const float*)d_in[19];
  const float* go   = (const float*)d_in[20]; const float* bo  = (const float*)d_in[21];
  const float* mo   = (const float*)d_in[22]; const float* vo  = (const float*)d_in[23];

  char* w8 = (char*)d_ws;
  float* fp    = (float*)(w8);
  float* fcb   = (float*)(w8 + (4u<<20));
  float* fus   = (float*)(w8 + (8u<<20));
  bf16*  fB    = (bf16*) (w8 + (12u<<20));   // [q][c]
  bf16*  fC    = (bf16*) (w8 + (14u<<20));   // [k][c]
  bf16*  fD    = (bf16*) (w8 + (16u<<20));   // [c][k]
  float* attnc = (float*)(w8 + (18u<<20));
  float* bn    = (float*)(w8 + (18u<<20) + 65536);

  k_prep<<<1, 512, 0, stream>>>(gp1,bp1,mp1,vp1, gc1,bc1,mc1,vc1, go,bo,mo,vo, bn);
  k_conv_in<<<dim3(16,8,4), 256, 0, stream>>>(x, wp1, wc1, bn, fp, fcb);
  k_qkv<<<dim3(8,12,4), 256, 0, stream>>>(fp, wb,bb, wc2,bc2, wd,bd, fB, fC, fD);
  k_chan_attn<<<dim3(64,4), 256, 0, stream>>>(fcb, attnc);
  k_pos_attn<<<dim3(64,4), 512, 0, stream>>>((const u16*)fB, (const u16*)fC, (const u16*)fD,
                                             fp, alp, fus);
  k_chan_apply<<<dim3(16,8,4), 256, 0, stream>>>(fcb, attnc, bet, fus);
  k_conv_out<<<dim3(8,32,4), 256, 0, stream>>>(fus, wo, bn, out);
}

// Round 10
// 316.047 us; speedup vs baseline: 1.0892x; 1.0590x over previous
//
#include <hip/hip_runtime.h>
#include <hip/hip_bf16.h>

typedef __hip_bfloat16 bf16;
typedef unsigned short u16;
typedef __attribute__((ext_vector_type(8))) short short8;
typedef __attribute__((ext_vector_type(4))) float f32x4;

#define HW 4096
#define NB (64*HW)

__device__ __forceinline__ f32x4 MFMA16(short8 a, short8 b, f32x4 c){
  return __builtin_amdgcn_mfma_f32_16x16x32_bf16(a, b, c, 0, 0, 0);
}

__device__ __forceinline__ short f2bf(float f){
  bf16 h = __float2bfloat16(f);
  return *(short*)&h;          // scalar pun — promoted to register (round-0 verified)
}

// diagnostic fill (fp32 output)
__global__ __launch_bounds__(256) void k_const(float* __restrict__ out, float v, int n){
  int i = blockIdx.x*256 + threadIdx.x;
  if (i < n) out[i] = v;
}

// ---------------- BN fold ----------------
// bn: [0,64) invp | [64,128) biasp | [128,192) invc | [192,256) biasc | [256,768) invo | [768,1280) biaso
__global__ __launch_bounds__(512) void k_prep(
    const float* __restrict__ gp, const float* __restrict__ bp,
    const float* __restrict__ mp, const float* __restrict__ vp,
    const float* __restrict__ gc, const float* __restrict__ bc,
    const float* __restrict__ mc, const float* __restrict__ vc,
    const float* __restrict__ go, const float* __restrict__ bo,
    const float* __restrict__ mo, const float* __restrict__ vo,
    float* __restrict__ bn){
  int t = threadIdx.x;
  if (t < 64){
    float iv = gp[t] * rsqrtf(vp[t] + 1e-5f);
    bn[t] = iv; bn[64+t] = bp[t] - mp[t]*iv;
    float ic = gc[t] * rsqrtf(vc[t] + 1e-5f);
    bn[128+t] = ic; bn[192+t] = bc[t] - mc[t]*ic;
  }
  float io = go[t] * rsqrtf(vo[t] + 1e-5f);
  bn[256+t] = io; bn[768+t] = bo[t] - mo[t]*io;
}

// ---------------- conv_in: 512->64 x2, BN folded, LDS weights ----------------
// grid (16 ptiles of 256 px, 8 cgroups, 4 b); cg<4 -> fp(wp1), cg>=4 -> fcb(wc1)
__global__ __launch_bounds__(256) void k_conv_in(
    const float* __restrict__ x, const float* __restrict__ wp1, const float* __restrict__ wc1,
    const float* __restrict__ bn, float* __restrict__ fp, float* __restrict__ fcb){
  __shared__ __align__(16) float Wl[512][16];
  const int t = threadIdx.x;
  const int cg = blockIdx.y, b = blockIdx.z;
  const bool isP = cg < 4;
  const int c0 = (cg & 3) * 16;
  const float* w = isP ? wp1 : wc1;
  const float* inv  = isP ? bn       : bn + 128;
  const float* bias = isP ? bn + 64  : bn + 192;
  float* outp = isP ? fp : fcb;
  for (int i = t; i < 8192; i += 256){
    int c = i & 15, k = i >> 4;
    Wl[k][c] = w[(size_t)(c0 + c)*512 + k];
  }
  __syncthreads();
  const int p = blockIdx.x*256 + t;
  const float* xb = x + (size_t)b*512*HW + p;
  float acc[16];
  #pragma unroll
  for (int i = 0; i < 16; i++) acc[i] = 0.f;
  for (int k = 0; k < 512; k++){
    float xv = xb[(size_t)k*HW];
    float4 w0 = *(const float4*)&Wl[k][0];
    float4 w1 = *(const float4*)&Wl[k][4];
    float4 w2 = *(const float4*)&Wl[k][8];
    float4 w3 = *(const float4*)&Wl[k][12];
    acc[0]=fmaf(w0.x,xv,acc[0]); acc[1]=fmaf(w0.y,xv,acc[1]); acc[2]=fmaf(w0.z,xv,acc[2]); acc[3]=fmaf(w0.w,xv,acc[3]);
    acc[4]=fmaf(w1.x,xv,acc[4]); acc[5]=fmaf(w1.y,xv,acc[5]); acc[6]=fmaf(w1.z,xv,acc[6]); acc[7]=fmaf(w1.w,xv,acc[7]);
    acc[8]=fmaf(w2.x,xv,acc[8]); acc[9]=fmaf(w2.y,xv,acc[9]); acc[10]=fmaf(w2.z,xv,acc[10]); acc[11]=fmaf(w2.w,xv,acc[11]);
    acc[12]=fmaf(w3.x,xv,acc[12]); acc[13]=fmaf(w3.y,xv,acc[13]); acc[14]=fmaf(w3.z,xv,acc[14]); acc[15]=fmaf(w3.w,xv,acc[15]);
  }
  const size_t base = (size_t)b*NB + p;
  #pragma unroll
  for (int i = 0; i < 16; i++){
    int c = c0 + i;
    outp[base + (size_t)c*HW] = fmaf(acc[i], inv[c], bias[c]);
  }
}

// ---------------- QKV convs; Q,K transposed [p][c], V natural [c][p] ----------------
// grid (8 ptiles of 512, 12 = 3 mats * 4 cgroups, 4 b)
__global__ __launch_bounds__(256) void k_qkv(
    const float* __restrict__ fp,
    const float* __restrict__ wb,  const float* __restrict__ bbv,
    const float* __restrict__ wc2, const float* __restrict__ bc2,
    const float* __restrict__ wd,  const float* __restrict__ bd,
    bf16* __restrict__ fB, bf16* __restrict__ fC, bf16* __restrict__ fD){
  __shared__ __align__(16) float Wl[64][16];
  __shared__ float Bl[16];
  const int t = threadIdx.x;
  const int mg = blockIdx.y, mat = mg >> 2, c0 = (mg & 3)*16, b = blockIdx.z;
  const float* w    = (mat == 0) ? wb  : (mat == 1 ? wc2 : wd);
  const float* bias = (mat == 0) ? bbv : (mat == 1 ? bc2 : bd);
  bf16* outp        = (mat == 0) ? fB  : (mat == 1 ? fC  : fD);
  for (int i = t; i < 1024; i += 256){
    int c = i & 15, k = i >> 4;
    Wl[k][c] = w[(size_t)(c0 + c)*64 + k];
  }
  if (t < 16) Bl[t] = bias[c0 + t];
  __syncthreads();
  const int p = blockIdx.x*512 + t*2;
  const float* in = fp + (size_t)b*NB + p;
  float2 acc[16];
  #pragma unroll
  for (int i = 0; i < 16; i++){ acc[i].x = 0.f; acc[i].y = 0.f; }
  for (int k = 0; k < 64; k++){
    float2 xv = *(const float2*)(in + (size_t)k*HW);
    float4 w0 = *(const float4*)&Wl[k][0];
    float4 w1 = *(const float4*)&Wl[k][4];
    float4 w2 = *(const float4*)&Wl[k][8];
    float4 w3 = *(const float4*)&Wl[k][12];
    float wv[16] = {w0.x,w0.y,w0.z,w0.w, w1.x,w1.y,w1.z,w1.w,
                    w2.x,w2.y,w2.z,w2.w, w3.x,w3.y,w3.z,w3.w};
    #pragma unroll
    for (int i = 0; i < 16; i++){
      acc[i].x = fmaf(wv[i], xv.x, acc[i].x);
      acc[i].y = fmaf(wv[i], xv.y, acc[i].y);
    }
  }
  if (mat < 2){
    bf16* ob = outp + (size_t)b*NB;
    #pragma unroll
    for (int i = 0; i < 16; i += 2){
      __hip_bfloat162 h0 = __float22bfloat162_rn(
          make_float2(acc[i].x + Bl[i], acc[i+1].x + Bl[i+1]));
      __hip_bfloat162 h1 = __float22bfloat162_rn(
          make_float2(acc[i].y + Bl[i], acc[i+1].y + Bl[i+1]));
      *(__hip_bfloat162*)&ob[(size_t)p*64 + c0 + i]     = h0;
      *(__hip_bfloat162*)&ob[(size_t)(p+1)*64 + c0 + i] = h1;
    }
  } else {
    const size_t base = (size_t)b*NB + p;
    #pragma unroll
    for (int i = 0; i < 16; i++){
      float bl = Bl[i];
      __hip_bfloat162 o2 = __float22bfloat162_rn(make_float2(acc[i].x + bl, acc[i].y + bl));
      *(__hip_bfloat162*)&outp[base + (size_t)(c0 + i)*HW] = o2;
    }
  }
}

// ---------------- channel attention: gram row + softmax(-S) ----------------
// grid (64 c, 4 b), 256 threads
__global__ __launch_bounds__(256) void k_chan_attn(
    const float* __restrict__ fcb, float* __restrict__ attn){
  __shared__ __align__(16) float rowc[4096];
  __shared__ float red[256];
  __shared__ float Srow[64];
  const int c = blockIdx.x, b = blockIdx.y, t = threadIdx.x;
  const float* fa = fcb + (size_t)b*NB;
  #pragma unroll
  for (int i = 0; i < 4; i++){
    int n = i*1024 + t*4;
    *(float4*)&rowc[n] = *(const float4*)&fa[(size_t)c*HW + n];
  }
  __syncthreads();
  const int d = t >> 2, part = t & 3;
  const float* frow = fa + (size_t)d*HW + part*1024;
  const float* rc = rowc + part*1024;
  float s = 0.f;
  for (int i = 0; i < 1024; i += 4){
    float4 xv = *(const float4*)&frow[i];
    float4 rv = *(const float4*)&rc[i];
    s += xv.x*rv.x + xv.y*rv.y + xv.z*rv.z + xv.w*rv.w;
  }
  red[t] = s;
  __syncthreads();
  if (part == 0) Srow[d] = red[t] + red[t+1] + red[t+2] + red[t+3];
  __syncthreads();
  if (t < 64){
    float z = -Srow[t];
    float m = z;
    #pragma unroll
    for (int off = 32; off; off >>= 1) m = fmaxf(m, __shfl_xor(m, off));
    float e = __expf(fminf(z - m, 0.f));
    float ss = e;
    #pragma unroll
    for (int off = 32; off; off >>= 1) ss += __shfl_xor(ss, off);
    attn[(size_t)b*4096 + (size_t)c*64 + t] = e / ss;
  }
}

// ---------------- position attention: split-K flash, swapped-QK^T, 2 blocks/CU ----------------
// QBLK=32: grid (128 qtiles, 4 b) = 512 blocks of 256 threads (4 waves =
// 2 split-K groups x 2 q-subtiles). LDS 71.7KB -> 2 blocks CO-RESIDENT per CU
// in INDEPENDENT barrier domains: when one block stalls on barrier/LDS/global
// latency the other issues (R7's single 512-thread block was 8 waves in ONE
// lockstep domain: 75% stall, MfmaUtil 7.5%). Same total MFMA work.
// Swapped QK^T: S^T = MFMA(A=K, B=Q), lane owns q=lr + its 32 keys = exactly
// the PV B-fragment (P never touches LDS). Direct staging (no reg prefetch --
// R8's prefetch arrays re-triggered scratch spill); exposed load latency is
// covered by the co-resident block.
// amdgpu_waves_per_eu(2,2): 2 waves/EU = 2 blocks/CU cap; keeps the allocator
// at the no-spill operating point (R7-verified; bare launch_bounds spilled).
__global__ __attribute__((amdgpu_flat_work_group_size(256, 256), amdgpu_waves_per_eu(2, 2)))
void k_pos_attn(
    const u16* __restrict__ fBt, const u16* __restrict__ fCt, const u16* __restrict__ fDv,
    const float* __restrict__ fpl, const float* __restrict__ alphap,
    float* __restrict__ fus){
  __shared__ __align__(16) u16 Kt[2][128*72];   // [group][k][c] pitch 72
  __shared__ __align__(16) u16 Vt[2][64*136];   // [group][c][k] pitch 136

  const int t = threadIdx.x;
  const int b = blockIdx.y, q0 = blockIdx.x*32;
  const int wv = t>>6;            // 0..3
  const int g  = wv>>1;           // split-K group (key half)
  const int wg = wv&1;            // q sub-tile (16 rows)
  const int lane = t&63, quad = lane>>4, lr = lane&15;
  const int tg = t & 127;         // thread-in-group
  const u16* Fb = fBt + (size_t)b*NB;
  const u16* Fc = fCt + (size_t)b*NB;
  const u16* Fd = fDv + (size_t)b*NB;

  // Q B-fragments ([q][c] layout): col j = lr -> q row q0 + wg*16 + lr
  const size_t qoff = (size_t)(q0 + wg*16 + lr)*64;
  short8 a0 = *(const short8*)&Fb[qoff + quad*8];
  short8 a1 = *(const short8*)&Fb[qoff + 32 + quad*8];

  // permuted K-row base: L(ks,lr) = 32*(ks>>1) + 8*(lr>>2) + 4*(ks&1) + (lr&3)
  const int krbase = ((lr>>2)<<3) + (lr&3);

  float m = -3.0e38f, l = 0.f;
  f32x4 accO[4];
  #pragma unroll
  for (int cs = 0; cs < 4; cs++) accO[cs] = (f32x4){0.f,0.f,0.f,0.f};

  // staging (128 threads/group): K row tg (full 64ch=128B); V row tg>>1, half (tg&1)
  const u16* Ksrc = Fc + (size_t)(g*2048 + tg)*64;
  const u16* Vsrc = Fd + (size_t)(tg>>1)*HW + g*2048 + (tg&1)*64;
  u16* Kdst = &Kt[g][tg*72];
  u16* Vdst = &Vt[g][(tg>>1)*136 + (tg&1)*64];

  for (int tile = 0; tile < 16; ++tile){
    __syncthreads();   // prev iteration consumed Kt/Vt
    {
      const uint4* ks = (const uint4*)(Ksrc + (size_t)tile*128*64);
      const uint4* vs = (const uint4*)(Vsrc + tile*128);
      #pragma unroll
      for (int i = 0; i < 8; i++) ((uint4*)Kdst)[i] = ks[i];
      #pragma unroll
      for (int i = 0; i < 8; i++) ((uint4*)Vdst)[i] = vs[i];
    }
    __syncthreads();   // staged tile visible

    // S^T = K Q^T: lane (quad,lr) reg r of subtile ks holds
    // S[q=lr][key = 32*(ks>>1) + 8*quad + 4*(ks&1) + r]
    f32x4 s[8];
    #pragma unroll
    for (int ks = 0; ks < 8; ks++){
      const int krow = krbase + ((ks>>1)<<5) + ((ks&1)<<2);
      short8 k0 = *(short8*)&Kt[g][krow*72 + quad*8];
      short8 k1 = *(short8*)&Kt[g][krow*72 + 32 + quad*8];
      f32x4 acc = {0.f,0.f,0.f,0.f};
      acc = MFMA16(k0, a0, acc);
      acc = MFMA16(k1, a1, acc);
      s[ks] = acc;
    }

    // online softmax, fully in registers; lane owns one q-row (q = lr)
    float t4[8];
    #pragma unroll
    for (int ks = 0; ks < 8; ks++)
      t4[ks] = fmaxf(fmaxf(s[ks][0], s[ks][1]), fmaxf(s[ks][2], s[ks][3]));
    float mx = fmaxf(fmaxf(fmaxf(t4[0],t4[1]), fmaxf(t4[2],t4[3])),
                     fmaxf(fmaxf(t4[4],t4[5]), fmaxf(t4[6],t4[7])));
    mx = fmaxf(mx, __shfl_xor(mx, 16));
    mx = fmaxf(mx, __shfl_xor(mx, 32));
    const float mn = fmaxf(m, mx);
    const float al = __expf(m - mn);
    m = mn;

    // exp + pack to bf16 PV B-fragments via element inserts (constant lanes only)
    short8 pf0, pf1, pf2, pf3;
    float rs = 0.f;
    #pragma unroll
    for (int ks = 0; ks < 8; ks++){
      float e0 = __expf(s[ks][0] - m);
      float e1 = __expf(s[ks][1] - m);
      float e2 = __expf(s[ks][2] - m);
      float e3 = __expf(s[ks][3] - m);
      rs += (e0 + e1) + (e2 + e3);
      const int o = (ks&1)*4;
      short b0 = f2bf(e0), b1 = f2bf(e1), b2 = f2bf(e2), b3 = f2bf(e3);
      if ((ks>>1) == 0){ pf0[o]=b0; pf0[o+1]=b1; pf0[o+2]=b2; pf0[o+3]=b3; }
      else if ((ks>>1) == 1){ pf1[o]=b0; pf1[o+1]=b1; pf1[o+2]=b2; pf1[o+3]=b3; }
      else if ((ks>>1) == 2){ pf2[o]=b0; pf2[o+1]=b1; pf2[o+2]=b2; pf2[o+3]=b3; }
      else            { pf3[o]=b0; pf3[o+1]=b1; pf3[o+2]=b2; pf3[o+3]=b3; }
    }
    rs += __shfl_xor(rs, 16);
    rs += __shfl_xor(rs, 32);
    l = l*al + rs;
    #pragma unroll
    for (int cs = 0; cs < 4; cs++) accO[cs] *= al;

    // O^T += V P^T : A = V[c][k] from LDS, B = P from registers
    #pragma unroll
    for (int cs = 0; cs < 4; cs++){
      short8 vf0 = *(short8*)&Vt[g][(cs*16+lr)*136 +  0 + quad*8];
      short8 vf1 = *(short8*)&Vt[g][(cs*16+lr)*136 + 32 + quad*8];
      short8 vf2 = *(short8*)&Vt[g][(cs*16+lr)*136 + 64 + quad*8];
      short8 vf3 = *(short8*)&Vt[g][(cs*16+lr)*136 + 96 + quad*8];
      accO[cs] = MFMA16(vf0, pf0, accO[cs]);
      accO[cs] = MFMA16(vf1, pf1, accO[cs]);
      accO[cs] = MFMA16(vf2, pf2, accO[cs]);
      accO[cs] = MFMA16(vf3, pf3, accO[cs]);
    }
  }
  // lane (quad,lr) reg r of accO[cs]: O^T[c = 16cs+4quad+r][q = wg*16+lr]

  // ---- flash-combine of the 2 groups' partials, in LDS (aliases Kt) ----
  __syncthreads();   // both groups' PV done; Kt free for reuse
  float* Ol = (float*)&Kt[0][0];      // 32 x pitch-69 f32 (8832 B <= 18432 B)
  float* Ml = Ol + 32*69;
  float* Ll = Ml + 32;
  if (g == 1){
    const int row = wg*16 + lr;       // 0..31
    #pragma unroll
    for (int cs = 0; cs < 4; cs++){
      #pragma unroll
      for (int r = 0; r < 4; r++)
        Ol[row*69 + cs*16 + quad*4 + r] = accO[cs][r];
    }
    if (quad == 0){ Ml[row] = m; Ll[row] = l; }
  }
  __syncthreads();
  if (g == 0){
    const float alp = alphap[0];
    const int row = wg*16 + lr;
    const float m1 = Ml[row], l1 = Ll[row];
    const float mt = fmaxf(m, m1);
    const float e0 = __expf(m - mt), e1 = __expf(m1 - mt);
    const float lt = fmaxf(l*e0 + l1*e1, 1e-20f);
    const float sc = alp / lt;
    #pragma unroll
    for (int cs = 0; cs < 4; cs++){
      #pragma unroll
      for (int r = 0; r < 4; r++){
        int idx = row*69 + cs*16 + quad*4 + r;
        Ol[idx] = (accO[cs][r]*e0 + Ol[idx]*e1) * sc;  // lane-local RAW across barrier
      }
    }
  }
  __syncthreads();

  // ---- coalesced epilogue: fus[c][q] = Ol[q][c] + fp[c][q] (64ch x 32q) ----
  {
    const int c = t >> 2, qs = (t & 3) * 8;
    const float* Fp = fpl + (size_t)b*NB + (size_t)c*HW + q0 + qs;
    float* Fo = fus + (size_t)b*NB + (size_t)c*HW + q0 + qs;
    float v[8];
    #pragma unroll
    for (int j = 0; j < 8; j++) v[j] = Ol[(qs+j)*69 + c] + Fp[j];
    *(float4*)&Fo[0] = make_float4(v[0],v[1],v[2],v[3]);
    *(float4*)&Fo[4] = make_float4(v[4],v[5],v[6],v[7]);
  }
}

// ---------------- channel apply: fus += beta*(attn@fa) + fcb ----------------
// grid (16 ptiles of 256, 8 cgroups of 8, 4 b)
__global__ __launch_bounds__(256) void k_chan_apply(
    const float* __restrict__ fcb, const float* __restrict__ attn,
    const float* __restrict__ betap, float* __restrict__ fus){
  __shared__ __align__(16) float Ar2[64][8];
  const int t = threadIdx.x;
  const int c0 = blockIdx.y*8, b = blockIdx.z;
  for (int i = t; i < 512; i += 256){
    int d = i >> 3, ci = i & 7;
    Ar2[d][ci] = attn[(size_t)b*4096 + (size_t)(c0 + ci)*64 + d];
  }
  __syncthreads();
  const int p = blockIdx.x*256 + t;
  const float* fa = fcb + (size_t)b*NB;
  float acc[8] = {0.f,0.f,0.f,0.f,0.f,0.f,0.f,0.f};
  for (int d = 0; d < 64; d++){
    float v = fa[(size_t)d*HW + p];
    float4 A0 = *(const float4*)&Ar2[d][0];
    float4 A1 = *(const float4*)&Ar2[d][4];
    acc[0]=fmaf(A0.x,v,acc[0]); acc[1]=fmaf(A0.y,v,acc[1]); acc[2]=fmaf(A0.z,v,acc[2]); acc[3]=fmaf(A0.w,v,acc[3]);
    acc[4]=fmaf(A1.x,v,acc[4]); acc[5]=fmaf(A1.y,v,acc[5]); acc[6]=fmaf(A1.z,v,acc[6]); acc[7]=fmaf(A1.w,v,acc[7]);
  }
  const float be = betap[0];
  #pragma unroll
  for (int i = 0; i < 8; i++){
    size_t idx = (size_t)b*NB + (size_t)(c0 + i)*HW + p;
    fus[idx] += fmaf(be, acc[i], fa[(size_t)(c0 + i)*HW + p]);
  }
}

// ---------------- out conv (64 -> 512) + BN, fp32 out, LDS weights ----------------
// grid (8 ptiles of 512, 32 ogroups of 16, 4 b)
__global__ __launch_bounds__(256) void k_conv_out(
    const float* __restrict__ fus, const float* __restrict__ wo,
    const float* __restrict__ bn, float* __restrict__ out){
  __shared__ __align__(16) float Wl[64][16];
  const int t = threadIdx.x;
  const int o0 = blockIdx.y*16, b = blockIdx.z;
  for (int i = t; i < 1024; i += 256){
    int o = i & 15, c = i >> 4;
    Wl[c][o] = wo[(size_t)(o0 + o)*64 + c];
  }
  __syncthreads();
  const int p = blockIdx.x*512 + t*2;
  const float* fu = fus + (size_t)b*NB + p;
  float2 acc[16];
  #pragma unroll
  for (int i = 0; i < 16; i++){ acc[i].x = 0.f; acc[i].y = 0.f; }
  for (int c = 0; c < 64; c++){
    float2 xv = *(const float2*)(fu + (size_t)c*HW);
    float4 w0 = *(const float4*)&Wl[c][0];
    float4 w1 = *(const float4*)&Wl[c][4];
    float4 w2 = *(const float4*)&Wl[c][8];
    float4 w3 = *(const float4*)&Wl[c][12];
    float wv[16] = {w0.x,w0.y,w0.z,w0.w, w1.x,w1.y,w1.z,w1.w,
                    w2.x,w2.y,w2.z,w2.w, w3.x,w3.y,w3.z,w3.w};
    #pragma unroll
    for (int i = 0; i < 16; i++){
      acc[i].x = fmaf(wv[i], xv.x, acc[i].x);
      acc[i].y = fmaf(wv[i], xv.y, acc[i].y);
    }
  }
  #pragma unroll
  for (int i = 0; i < 16; i++){
    int o = o0 + i;
    float iv = bn[256+o], bs = bn[768+o];
    float* op = &out[(size_t)b*512*HW + (size_t)o*HW + p];
    op[0] = fmaf(acc[i].x, iv, bs);
    op[1] = fmaf(acc[i].y, iv, bs);
  }
}

extern "C" void kernel_launch(void* const* d_in, const int* in_sizes, int n_in,
                              void* d_out, int out_size, void* d_ws, size_t ws_size,
                              hipStream_t stream){
  static const int dictSz[24] = {8388608,32768,64,64,64,64,32768,64,64,64,64,
                                 4096,64,4096,64,4096,64,1,1,32768,512,512,512,512};
  bool dictOk = (n_in == 24);
  if (dictOk){
    for (int i = 0; i < 24; i++) if (in_sizes[i] != dictSz[i]) dictOk = false;
  }
  bool wsOk = (ws_size >= (size_t)(19u << 20));
  float* out = (float*)d_out;
  if (!dictOk){ k_const<<<(out_size+255)/256, 256, 0, stream>>>(out, 32.f, out_size); return; }
  if (!wsOk)  { k_const<<<(out_size+255)/256, 256, 0, stream>>>(out, 48.f, out_size); return; }

  const float* x    = (const float*)d_in[0];
  const float* wp1  = (const float*)d_in[1];
  const float* gp1  = (const float*)d_in[2];  const float* bp1 = (const float*)d_in[3];
  const float* mp1  = (const float*)d_in[4];  const float* vp1 = (const float*)d_in[5];
  const float* wc1  = (const float*)d_in[6];
  const float* gc1  = (const float*)d_in[7];  const float* bc1 = (const float*)d_in[8];
  const float* mc1  = (const float*)d_in[9];  const float* vc1 = (const float*)d_in[10];
  const float* wb   = (const float*)d_in[11]; const float* bb  = (const float*)d_in[12];
  const float* wc2  = (const float*)d_in[13]; const float* bc2 = (const float*)d_in[14];
  const float* wd   = (const float*)d_in[15]; const float* bd  = (const float*)d_in[16];
  const float* alp  = (const float*)d_in[17]; const float* bet = (const float*)d_in[18];
  const float* wo   = (const float*)d_in[19];
  const float* go   = (const float*)d_in[20]; const float* bo  = (const float*)d_in[21];
  const float* mo   = (const float*)d_in[22]; const float* vo  = (const float*)d_in[23];

  char* w8 = (char*)d_ws;
  float* fp    = (float*)(w8);
  float* fcb   = (float*)(w8 + (4u<<20));
  float* fus   = (float*)(w8 + (8u<<20));
  bf16*  fB    = (bf16*) (w8 + (12u<<20));   // [q][c]
  bf16*  fC    = (bf16*) (w8 + (14u<<20));   // [k][c]
  bf16*  fD    = (bf16*) (w8 + (16u<<20));   // [c][k]
  float* attnc = (float*)(w8 + (18u<<20));
  float* bn    = (float*)(w8 + (18u<<20) + 65536);

  k_prep<<<1, 512, 0, stream>>>(gp1,bp1,mp1,vp1, gc1,bc1,mc1,vc1, go,bo,mo,vo, bn);
  k_conv_in<<<dim3(16,8,4), 256, 0, stream>>>(x, wp1, wc1, bn, fp, fcb);
  k_qkv<<<dim3(8,12,4), 256, 0, stream>>>(fp, wb,bb, wc2,bc2, wd,bd, fB, fC, fD);
  k_chan_attn<<<dim3(64,4), 256, 0, stream>>>(fcb, attnc);
  k_pos_attn<<<dim3(128,4), 256, 0, stream>>>((const u16*)fB, (const u16*)fC, (const u16*)fD,
                                              fp, alp, fus);
  k_chan_apply<<<dim3(16,8,4), 256, 0, stream>>>(fcb, attnc, bet, fus);
  k_conv_out<<<dim3(8,32,4), 256, 0, stream>>>(fus, wo, bn, out);
}

// Round 11
// 314.703 us; speedup vs baseline: 1.0938x; 1.0043x over previous
//
#include <hip/hip_runtime.h>
#include <hip/hip_bf16.h>

typedef __hip_bfloat16 bf16;
typedef unsigned short u16;
typedef __attribute__((ext_vector_type(8))) short short8;
typedef __attribute__((ext_vector_type(4))) float f32x4;

#define HW 4096
#define NB (64*HW)

__device__ __forceinline__ f32x4 MFMA16(short8 a, short8 b, f32x4 c){
  return __builtin_amdgcn_mfma_f32_16x16x32_bf16(a, b, c, 0, 0, 0);
}

__device__ __forceinline__ short f2bf(float f){
  bf16 h = __float2bfloat16(f);
  return *(short*)&h;          // scalar pun — promoted to register (round-0 verified)
}

// diagnostic fill (fp32 output)
__global__ __launch_bounds__(256) void k_const(float* __restrict__ out, float v, int n){
  int i = blockIdx.x*256 + threadIdx.x;
  if (i < n) out[i] = v;
}

// ---------------- BN fold ----------------
// bn: [0,64) invp | [64,128) biasp | [128,192) invc | [192,256) biasc | [256,768) invo | [768,1280) biaso
__global__ __launch_bounds__(512) void k_prep(
    const float* __restrict__ gp, const float* __restrict__ bp,
    const float* __restrict__ mp, const float* __restrict__ vp,
    const float* __restrict__ gc, const float* __restrict__ bc,
    const float* __restrict__ mc, const float* __restrict__ vc,
    const float* __restrict__ go, const float* __restrict__ bo,
    const float* __restrict__ mo, const float* __restrict__ vo,
    float* __restrict__ bn){
  int t = threadIdx.x;
  if (t < 64){
    float iv = gp[t] * rsqrtf(vp[t] + 1e-5f);
    bn[t] = iv; bn[64+t] = bp[t] - mp[t]*iv;
    float ic = gc[t] * rsqrtf(vc[t] + 1e-5f);
    bn[128+t] = ic; bn[192+t] = bc[t] - mc[t]*ic;
  }
  float io = go[t] * rsqrtf(vo[t] + 1e-5f);
  bn[256+t] = io; bn[768+t] = bo[t] - mo[t]*io;
}

// ---------------- weight transpose: wave-uniform-friendly layouts ----------------
// wTin[k][c] (512x128): c<64 from wp1[c][k], c>=64 from wc1[c-64][k]
// wTout[c][o] (64x512): from wo[o][c]
// grid (384) x 256
__global__ __launch_bounds__(256) void k_wtrans(
    const float* __restrict__ wp1, const float* __restrict__ wc1,
    const float* __restrict__ wo,
    float* __restrict__ wTin, float* __restrict__ wTout){
  int idx = blockIdx.x*256 + threadIdx.x;
  if (idx < 65536){
    int k = idx >> 7, c = idx & 127;
    wTin[idx] = (c < 64) ? wp1[(size_t)c*512 + k] : wc1[(size_t)(c-64)*512 + k];
  } else {
    int idx2 = idx - 65536;
    int c = idx2 >> 9, o = idx2 & 511;
    wTout[idx2] = wo[(size_t)o*64 + c];
  }
}

// ---------------- conv_in: 512->64 x2, BN folded, SGPR weights (no LDS) ----------------
// grid (16 ptiles of 256 px, 8 cgroups, 4 b); cg<4 -> fp(wp1), cg>=4 -> fcb(wc1)
// Weights read via wave-uniform pointer into wTin -> scalar(K$) pipe, NOT LDS.
// (R10 profile: old LDS version was bound by the shared LDS pipe: 4 waves x
// 4 ds_read_b128 x ~12cyc = 192 cyc/iter = measured 192 cyc/iter; VALU 17%.)
__global__ __launch_bounds__(256) void k_conv_in(
    const float* __restrict__ x, const float* __restrict__ wT,
    const float* __restrict__ bn, float* __restrict__ fp, float* __restrict__ fcb){
  const int t = threadIdx.x;
  const int cg = blockIdx.y, b = blockIdx.z;
  const bool isP = cg < 4;
  const int c0 = (cg & 3) * 16;
  const float* inv  = isP ? bn       : bn + 128;
  const float* bias = isP ? bn + 64  : bn + 192;
  float* outp = isP ? fp : fcb;
  const int p = blockIdx.x*256 + t;
  const float* xb = x + (size_t)b*512*HW + p;
  const float* wrow = wT + cg*16;       // wT[k][128]; uniform across lanes
  float acc[16];
  #pragma unroll
  for (int i = 0; i < 16; i++) acc[i] = 0.f;
  #pragma unroll 8
  for (int k = 0; k < 512; k++){
    float xv = xb[(size_t)k*HW];
    const float4* wr = (const float4*)(wrow + (size_t)k*128);
    float4 w0 = wr[0];
    float4 w1 = wr[1];
    float4 w2 = wr[2];
    float4 w3 = wr[3];
    acc[0]=fmaf(w0.x,xv,acc[0]); acc[1]=fmaf(w0.y,xv,acc[1]); acc[2]=fmaf(w0.z,xv,acc[2]); acc[3]=fmaf(w0.w,xv,acc[3]);
    acc[4]=fmaf(w1.x,xv,acc[4]); acc[5]=fmaf(w1.y,xv,acc[5]); acc[6]=fmaf(w1.z,xv,acc[6]); acc[7]=fmaf(w1.w,xv,acc[7]);
    acc[8]=fmaf(w2.x,xv,acc[8]); acc[9]=fmaf(w2.y,xv,acc[9]); acc[10]=fmaf(w2.z,xv,acc[10]); acc[11]=fmaf(w2.w,xv,acc[11]);
    acc[12]=fmaf(w3.x,xv,acc[12]); acc[13]=fmaf(w3.y,xv,acc[13]); acc[14]=fmaf(w3.z,xv,acc[14]); acc[15]=fmaf(w3.w,xv,acc[15]);
  }
  const size_t base = (size_t)b*NB + p;
  #pragma unroll
  for (int i = 0; i < 16; i++){
    int c = c0 + i;
    outp[base + (size_t)c*HW] = fmaf(acc[i], inv[c], bias[c]);
  }
}

// ---------------- QKV convs; Q,K transposed [p][c], V natural [c][p] ----------------
// grid (8 ptiles of 512, 12 = 3 mats * 4 cgroups, 4 b)
__global__ __launch_bounds__(256) void k_qkv(
    const float* __restrict__ fp,
    const float* __restrict__ wb,  const float* __restrict__ bbv,
    const float* __restrict__ wc2, const float* __restrict__ bc2,
    const float* __restrict__ wd,  const float* __restrict__ bd,
    bf16* __restrict__ fB, bf16* __restrict__ fC, bf16* __restrict__ fD){
  __shared__ __align__(16) float Wl[64][16];
  __shared__ float Bl[16];
  const int t = threadIdx.x;
  const int mg = blockIdx.y, mat = mg >> 2, c0 = (mg & 3)*16, b = blockIdx.z;
  const float* w    = (mat == 0) ? wb  : (mat == 1 ? wc2 : wd);
  const float* bias = (mat == 0) ? bbv : (mat == 1 ? bc2 : bd);
  bf16* outp        = (mat == 0) ? fB  : (mat == 1 ? fC  : fD);
  for (int i = t; i < 1024; i += 256){
    int c = i & 15, k = i >> 4;
    Wl[k][c] = w[(size_t)(c0 + c)*64 + k];
  }
  if (t < 16) Bl[t] = bias[c0 + t];
  __syncthreads();
  const int p = blockIdx.x*512 + t*2;
  const float* in = fp + (size_t)b*NB + p;
  float2 acc[16];
  #pragma unroll
  for (int i = 0; i < 16; i++){ acc[i].x = 0.f; acc[i].y = 0.f; }
  for (int k = 0; k < 64; k++){
    float2 xv = *(const float2*)(in + (size_t)k*HW);
    float4 w0 = *(const float4*)&Wl[k][0];
    float4 w1 = *(const float4*)&Wl[k][4];
    float4 w2 = *(const float4*)&Wl[k][8];
    float4 w3 = *(const float4*)&Wl[k][12];
    float wv[16] = {w0.x,w0.y,w0.z,w0.w, w1.x,w1.y,w1.z,w1.w,
                    w2.x,w2.y,w2.z,w2.w, w3.x,w3.y,w3.z,w3.w};
    #pragma unroll
    for (int i = 0; i < 16; i++){
      acc[i].x = fmaf(wv[i], xv.x, acc[i].x);
      acc[i].y = fmaf(wv[i], xv.y, acc[i].y);
    }
  }
  if (mat < 2){
    bf16* ob = outp + (size_t)b*NB;
    #pragma unroll
    for (int i = 0; i < 16; i += 2){
      __hip_bfloat162 h0 = __float22bfloat162_rn(
          make_float2(acc[i].x + Bl[i], acc[i+1].x + Bl[i+1]));
      __hip_bfloat162 h1 = __float22bfloat162_rn(
          make_float2(acc[i].y + Bl[i], acc[i+1].y + Bl[i+1]));
      *(__hip_bfloat162*)&ob[(size_t)p*64 + c0 + i]     = h0;
      *(__hip_bfloat162*)&ob[(size_t)(p+1)*64 + c0 + i] = h1;
    }
  } else {
    const size_t base = (size_t)b*NB + p;
    #pragma unroll
    for (int i = 0; i < 16; i++){
      float bl = Bl[i];
      __hip_bfloat162 o2 = __float22bfloat162_rn(make_float2(acc[i].x + bl, acc[i].y + bl));
      *(__hip_bfloat162*)&outp[base + (size_t)(c0 + i)*HW] = o2;
    }
  }
}

// ---------------- channel attention: gram row + softmax(-S) ----------------
// grid (64 c, 4 b), 256 threads
__global__ __launch_bounds__(256) void k_chan_attn(
    const float* __restrict__ fcb, float* __restrict__ attn){
  __shared__ __align__(16) float rowc[4096];
  __shared__ float red[256];
  __shared__ float Srow[64];
  const int c = blockIdx.x, b = blockIdx.y, t = threadIdx.x;
  const float* fa = fcb + (size_t)b*NB;
  #pragma unroll
  for (int i = 0; i < 4; i++){
    int n = i*1024 + t*4;
    *(float4*)&rowc[n] = *(const float4*)&fa[(size_t)c*HW + n];
  }
  __syncthreads();
  const int d = t >> 2, part = t & 3;
  const float* frow = fa + (size_t)d*HW + part*1024;
  const float* rc = rowc + part*1024;
  float s = 0.f;
  for (int i = 0; i < 1024; i += 4){
    float4 xv = *(const float4*)&frow[i];
    float4 rv = *(const float4*)&rc[i];
    s += xv.x*rv.x + xv.y*rv.y + xv.z*rv.z + xv.w*rv.w;
  }
  red[t] = s;
  __syncthreads();
  if (part == 0) Srow[d] = red[t] + red[t+1] + red[t+2] + red[t+3];
  __syncthreads();
  if (t < 64){
    float z = -Srow[t];
    float m = z;
    #pragma unroll
    for (int off = 32; off; off >>= 1) m = fmaxf(m, __shfl_xor(m, off));
    float e = __expf(fminf(z - m, 0.f));
    float ss = e;
    #pragma unroll
    for (int off = 32; off; off >>= 1) ss += __shfl_xor(ss, off);
    attn[(size_t)b*4096 + (size_t)c*64 + t] = e / ss;
  }
}

// ---------------- position attention: split-K flash, swapped-QK^T, 2 blocks/CU ----------------
// QBLK=32: grid (128 qtiles, 4 b) = 512 blocks of 256 threads (4 waves =
// 2 split-K groups x 2 q-subtiles). LDS 71.7KB -> 2 blocks CO-RESIDENT per CU
// in INDEPENDENT barrier domains (R10: 88.9 -> <81 us). Same total MFMA work.
// Swapped QK^T: S^T = MFMA(A=K, B=Q), lane owns q=lr + its 32 keys = exactly
// the PV B-fragment (P never touches LDS). Direct staging (no reg prefetch --
// R8's prefetch arrays re-triggered scratch spill).
// amdgpu_waves_per_eu(2,2): keeps the allocator at the no-spill operating point.
__global__ __attribute__((amdgpu_flat_work_group_size(256, 256), amdgpu_waves_per_eu(2, 2)))
void k_pos_attn(
    const u16* __restrict__ fBt, const u16* __restrict__ fCt, const u16* __restrict__ fDv,
    const float* __restrict__ fpl, const float* __restrict__ alphap,
    float* __restrict__ fus){
  __shared__ __align__(16) u16 Kt[2][128*72];   // [group][k][c] pitch 72
  __shared__ __align__(16) u16 Vt[2][64*136];   // [group][c][k] pitch 136

  const int t = threadIdx.x;
  const int b = blockIdx.y, q0 = blockIdx.x*32;
  const int wv = t>>6;            // 0..3
  const int g  = wv>>1;           // split-K group (key half)
  const int wg = wv&1;            // q sub-tile (16 rows)
  const int lane = t&63, quad = lane>>4, lr = lane&15;
  const int tg = t & 127;         // thread-in-group
  const u16* Fb = fBt + (size_t)b*NB;
  const u16* Fc = fCt + (size_t)b*NB;
  const u16* Fd = fDv + (size_t)b*NB;

  // Q B-fragments ([q][c] layout): col j = lr -> q row q0 + wg*16 + lr
  const size_t qoff = (size_t)(q0 + wg*16 + lr)*64;
  short8 a0 = *(const short8*)&Fb[qoff + quad*8];
  short8 a1 = *(const short8*)&Fb[qoff + 32 + quad*8];

  // permuted K-row base: L(ks,lr) = 32*(ks>>1) + 8*(lr>>2) + 4*(ks&1) + (lr&3)
  const int krbase = ((lr>>2)<<3) + (lr&3);

  float m = -3.0e38f, l = 0.f;
  f32x4 accO[4];
  #pragma unroll
  for (int cs = 0; cs < 4; cs++) accO[cs] = (f32x4){0.f,0.f,0.f,0.f};

  // staging (128 threads/group): K row tg (full 64ch=128B); V row tg>>1, half (tg&1)
  const u16* Ksrc = Fc + (size_t)(g*2048 + tg)*64;
  const u16* Vsrc = Fd + (size_t)(tg>>1)*HW + g*2048 + (tg&1)*64;
  u16* Kdst = &Kt[g][tg*72];
  u16* Vdst = &Vt[g][(tg>>1)*136 + (tg&1)*64];

  for (int tile = 0; tile < 16; ++tile){
    __syncthreads();   // prev iteration consumed Kt/Vt
    {
      const uint4* ks = (const uint4*)(Ksrc + (size_t)tile*128*64);
      const uint4* vs = (const uint4*)(Vsrc + tile*128);
      #pragma unroll
      for (int i = 0; i < 8; i++) ((uint4*)Kdst)[i] = ks[i];
      #pragma unroll
      for (int i = 0; i < 8; i++) ((uint4*)Vdst)[i] = vs[i];
    }
    __syncthreads();   // staged tile visible

    // S^T = K Q^T: lane (quad,lr) reg r of subtile ks holds
    // S[q=lr][key = 32*(ks>>1) + 8*quad + 4*(ks&1) + r]
    f32x4 s[8];
    #pragma unroll
    for (int ks = 0; ks < 8; ks++){
      const int krow = krbase + ((ks>>1)<<5) + ((ks&1)<<2);
      short8 k0 = *(short8*)&Kt[g][krow*72 + quad*8];
      short8 k1 = *(short8*)&Kt[g][krow*72 + 32 + quad*8];
      f32x4 acc = {0.f,0.f,0.f,0.f};
      acc = MFMA16(k0, a0, acc);
      acc = MFMA16(k1, a1, acc);
      s[ks] = acc;
    }

    // online softmax, fully in registers; lane owns one q-row (q = lr)
    float t4[8];
    #pragma unroll
    for (int ks = 0; ks < 8; ks++)
      t4[ks] = fmaxf(fmaxf(s[ks][0], s[ks][1]), fmaxf(s[ks][2], s[ks][3]));
    float mx = fmaxf(fmaxf(fmaxf(t4[0],t4[1]), fmaxf(t4[2],t4[3])),
                     fmaxf(fmaxf(t4[4],t4[5]), fmaxf(t4[6],t4[7])));
    mx = fmaxf(mx, __shfl_xor(mx, 16));
    mx = fmaxf(mx, __shfl_xor(mx, 32));
    const float mn = fmaxf(m, mx);
    const float al = __expf(m - mn);
    m = mn;

    // exp + pack to bf16 PV B-fragments via element inserts (constant lanes only)
    short8 pf0, pf1, pf2, pf3;
    float rs = 0.f;
    #pragma unroll
    for (int ks = 0; ks < 8; ks++){
      float e0 = __expf(s[ks][0] - m);
      float e1 = __expf(s[ks][1] - m);
      float e2 = __expf(s[ks][2] - m);
      float e3 = __expf(s[ks][3] - m);
      rs += (e0 + e1) + (e2 + e3);
      const int o = (ks&1)*4;
      short b0 = f2bf(e0), b1 = f2bf(e1), b2 = f2bf(e2), b3 = f2bf(e3);
      if ((ks>>1) == 0){ pf0[o]=b0; pf0[o+1]=b1; pf0[o+2]=b2; pf0[o+3]=b3; }
      else if ((ks>>1) == 1){ pf1[o]=b0; pf1[o+1]=b1; pf1[o+2]=b2; pf1[o+3]=b3; }
      else if ((ks>>1) == 2){ pf2[o]=b0; pf2[o+1]=b1; pf2[o+2]=b2; pf2[o+3]=b3; }
      else            { pf3[o]=b0; pf3[o+1]=b1; pf3[o+2]=b2; pf3[o+3]=b3; }
    }
    rs += __shfl_xor(rs, 16);
    rs += __shfl_xor(rs, 32);
    l = l*al + rs;
    #pragma unroll
    for (int cs = 0; cs < 4; cs++) accO[cs] *= al;

    // O^T += V P^T : A = V[c][k] from LDS, B = P from registers
    #pragma unroll
    for (int cs = 0; cs < 4; cs++){
      short8 vf0 = *(short8*)&Vt[g][(cs*16+lr)*136 +  0 + quad*8];
      short8 vf1 = *(short8*)&Vt[g][(cs*16+lr)*136 + 32 + quad*8];
      short8 vf2 = *(short8*)&Vt[g][(cs*16+lr)*136 + 64 + quad*8];
      short8 vf3 = *(short8*)&Vt[g][(cs*16+lr)*136 + 96 + quad*8];
      accO[cs] = MFMA16(vf0, pf0, accO[cs]);
      accO[cs] = MFMA16(vf1, pf1, accO[cs]);
      accO[cs] = MFMA16(vf2, pf2, accO[cs]);
      accO[cs] = MFMA16(vf3, pf3, accO[cs]);
    }
  }
  // lane (quad,lr) reg r of accO[cs]: O^T[c = 16cs+4quad+r][q = wg*16+lr]

  // ---- flash-combine of the 2 groups' partials, in LDS (aliases Kt) ----
  __syncthreads();   // both groups' PV done; Kt free for reuse
  float* Ol = (float*)&Kt[0][0];      // 32 x pitch-69 f32 (8832 B <= 18432 B)
  float* Ml = Ol + 32*69;
  float* Ll = Ml + 32;
  if (g == 1){
    const int row = wg*16 + lr;       // 0..31
    #pragma unroll
    for (int cs = 0; cs < 4; cs++){
      #pragma unroll
      for (int r = 0; r < 4; r++)
        Ol[row*69 + cs*16 + quad*4 + r] = accO[cs][r];
    }
    if (quad == 0){ Ml[row] = m; Ll[row] = l; }
  }
  __syncthreads();
  if (g == 0){
    const float alp = alphap[0];
    const int row = wg*16 + lr;
    const float m1 = Ml[row], l1 = Ll[row];
    const float mt = fmaxf(m, m1);
    const float e0 = __expf(m - mt), e1 = __expf(m1 - mt);
    const float lt = fmaxf(l*e0 + l1*e1, 1e-20f);
    const float sc = alp / lt;
    #pragma unroll
    for (int cs = 0; cs < 4; cs++){
      #pragma unroll
      for (int r = 0; r < 4; r++){
        int idx = row*69 + cs*16 + quad*4 + r;
        Ol[idx] = (accO[cs][r]*e0 + Ol[idx]*e1) * sc;  // lane-local RAW across barrier
      }
    }
  }
  __syncthreads();

  // ---- coalesced epilogue: fus[c][q] = Ol[q][c] + fp[c][q] (64ch x 32q) ----
  {
    const int c = t >> 2, qs = (t & 3) * 8;
    const float* Fp = fpl + (size_t)b*NB + (size_t)c*HW + q0 + qs;
    float* Fo = fus + (size_t)b*NB + (size_t)c*HW + q0 + qs;
    float v[8];
    #pragma unroll
    for (int j = 0; j < 8; j++) v[j] = Ol[(qs+j)*69 + c] + Fp[j];
    *(float4*)&Fo[0] = make_float4(v[0],v[1],v[2],v[3]);
    *(float4*)&Fo[4] = make_float4(v[4],v[5],v[6],v[7]);
  }
}

// ---------------- channel apply: fus += beta*(attn@fa) + fcb ----------------
// grid (16 ptiles of 256, 8 cgroups of 8, 4 b)
__global__ __launch_bounds__(256) void k_chan_apply(
    const float* __restrict__ fcb, const float* __restrict__ attn,
    const float* __restrict__ betap, float* __restrict__ fus){
  __shared__ __align__(16) float Ar2[64][8];
  const int t = threadIdx.x;
  const int c0 = blockIdx.y*8, b = blockIdx.z;
  for (int i = t; i < 512; i += 256){
    int d = i >> 3, ci = i & 7;
    Ar2[d][ci] = attn[(size_t)b*4096 + (size_t)(c0 + ci)*64 + d];
  }
  __syncthreads();
  const int p = blockIdx.x*256 + t;
  const float* fa = fcb + (size_t)b*NB;
  float acc[8] = {0.f,0.f,0.f,0.f,0.f,0.f,0.f,0.f};
  for (int d = 0; d < 64; d++){
    float v = fa[(size_t)d*HW + p];
    float4 A0 = *(const float4*)&Ar2[d][0];
    float4 A1 = *(const float4*)&Ar2[d][4];
    acc[0]=fmaf(A0.x,v,acc[0]); acc[1]=fmaf(A0.y,v,acc[1]); acc[2]=fmaf(A0.z,v,acc[2]); acc[3]=fmaf(A0.w,v,acc[3]);
    acc[4]=fmaf(A1.x,v,acc[4]); acc[5]=fmaf(A1.y,v,acc[5]); acc[6]=fmaf(A1.z,v,acc[6]); acc[7]=fmaf(A1.w,v,acc[7]);
  }
  const float be = betap[0];
  #pragma unroll
  for (int i = 0; i < 8; i++){
    size_t idx = (size_t)b*NB + (size_t)(c0 + i)*HW + p;
    fus[idx] += fmaf(be, acc[i], fa[(size_t)(c0 + i)*HW + p]);
  }
}

// ---------------- out conv (64 -> 512) + BN, fp32 out, SGPR weights (no LDS) ----------------
// grid (8 ptiles of 512, 32 ogroups of 16, 4 b); woT[c][512] read wave-uniform
__global__ __launch_bounds__(256) void k_conv_out(
    const float* __restrict__ fus, const float* __restrict__ woT,
    const float* __restrict__ bn, float* __restrict__ out){
  const int t = threadIdx.x;
  const int o0 = blockIdx.y*16, b = blockIdx.z;
  const int p = blockIdx.x*512 + t*2;
  const float* fu = fus + (size_t)b*NB + p;
  const float* wrow = woT + o0;         // woT[c][512]; uniform across lanes
  float2 acc[16];
  #pragma unroll
  for (int i = 0; i < 16; i++){ acc[i].x = 0.f; acc[i].y = 0.f; }
  #pragma unroll 4
  for (int c = 0; c < 64; c++){
    float2 xv = *(const float2*)(fu + (size_t)c*HW);
    const float4* wr = (const float4*)(wrow + (size_t)c*512);
    float4 w0 = wr[0];
    float4 w1 = wr[1];
    float4 w2 = wr[2];
    float4 w3 = wr[3];
    float wv[16] = {w0.x,w0.y,w0.z,w0.w, w1.x,w1.y,w1.z,w1.w,
                    w2.x,w2.y,w2.z,w2.w, w3.x,w3.y,w3.z,w3.w};
    #pragma unroll
    for (int i = 0; i < 16; i++){
      acc[i].x = fmaf(wv[i], xv.x, acc[i].x);
      acc[i].y = fmaf(wv[i], xv.y, acc[i].y);
    }
  }
  #pragma unroll
  for (int i = 0; i < 16; i++){
    int o = o0 + i;
    float iv = bn[256+o], bs = bn[768+o];
    float* op = &out[(size_t)b*512*HW + (size_t)o*HW + p];
    op[0] = fmaf(acc[i].x, iv, bs);
    op[1] = fmaf(acc[i].y, iv, bs);
  }
}

extern "C" void kernel_launch(void* const* d_in, const int* in_sizes, int n_in,
                              void* d_out, int out_size, void* d_ws, size_t ws_size,
                              hipStream_t stream){
  static const int dictSz[24] = {8388608,32768,64,64,64,64,32768,64,64,64,64,
                                 4096,64,4096,64,4096,64,1,1,32768,512,512,512,512};
  bool dictOk = (n_in == 24);
  if (dictOk){
    for (int i = 0; i < 24; i++) if (in_sizes[i] != dictSz[i]) dictOk = false;
  }
  bool wsOk = (ws_size >= (size_t)(19u << 20));
  float* out = (float*)d_out;
  if (!dictOk){ k_const<<<(out_size+255)/256, 256, 0, stream>>>(out, 32.f, out_size); return; }
  if (!wsOk)  { k_const<<<(out_size+255)/256, 256, 0, stream>>>(out, 48.f, out_size); return; }

  const float* x    = (const float*)d_in[0];
  const float* wp1  = (const float*)d_in[1];
  const float* gp1  = (const float*)d_in[2];  const float* bp1 = (const float*)d_in[3];
  const float* mp1  = (const float*)d_in[4];  const float* vp1 = (const float*)d_in[5];
  const float* wc1  = (const float*)d_in[6];
  const float* gc1  = (const float*)d_in[7];  const float* bc1 = (const float*)d_in[8];
  const float* mc1  = (const float*)d_in[9];  const float* vc1 = (const float*)d_in[10];
  const float* wb   = (const float*)d_in[11]; const float* bb  = (const float*)d_in[12];
  const float* wc2  = (const float*)d_in[13]; const float* bc2 = (const float*)d_in[14];
  const float* wd   = (const float*)d_in[15]; const float* bd  = (const float*)d_in[16];
  const float* alp  = (const float*)d_in[17]; const float* bet = (const float*)d_in[18];
  const float* wo   = (const float*)d_in[19];
  const float* go   = (const float*)d_in[20]; const float* bo  = (const float*)d_in[21];
  const float* mo   = (const float*)d_in[22]; const float* vo  = (const float*)d_in[23];

  char* w8 = (char*)d_ws;
  float* fp    = (float*)(w8);
  float* fcb   = (float*)(w8 + (4u<<20));
  float* fus   = (float*)(w8 + (8u<<20));
  bf16*  fB    = (bf16*) (w8 + (12u<<20));   // [q][c]
  bf16*  fC    = (bf16*) (w8 + (14u<<20));   // [k][c]
  bf16*  fD    = (bf16*) (w8 + (16u<<20));   // [c][k]
  float* attnc = (float*)(w8 + (18u<<20));                       // 64KB
  float* bn    = (float*)(w8 + (18u<<20) + 65536);               // 5KB
  float* wTin  = (float*)(w8 + (18u<<20) + 131072);              // 256KB [512][128]
  float* wTout = (float*)(w8 + (18u<<20) + 131072 + 262144);     // 128KB [64][512]

  k_prep<<<1, 512, 0, stream>>>(gp1,bp1,mp1,vp1, gc1,bc1,mc1,vc1, go,bo,mo,vo, bn);
  k_wtrans<<<384, 256, 0, stream>>>(wp1, wc1, wo, wTin, wTout);
  k_conv_in<<<dim3(16,8,4), 256, 0, stream>>>(x, wTin, bn, fp, fcb);
  k_qkv<<<dim3(8,12,4), 256, 0, stream>>>(fp, wb,bb, wc2,bc2, wd,bd, fB, fC, fD);
  k_chan_attn<<<dim3(64,4), 256, 0, stream>>>(fcb, attnc);
  k_pos_attn<<<dim3(128,4), 256, 0, stream>>>((const u16*)fB, (const u16*)fC, (const u16*)fD,
                                              fp, alp, fus);
  k_chan_apply<<<dim3(16,8,4), 256, 0, stream>>>(fcb, attnc, bet, fus);
  k_conv_out<<<dim3(8,32,4), 256, 0, stream>>>(fus, wTout, bn, out);
}